// Round 9
// baseline (647.517 us; speedup 1.0000x reference)
//
#include <hip/hip_runtime.h>
#include <hip/hip_bf16.h>
#include <math.h>

#define N_NODES 50000
#define N_EDGES 800000
#define CDIM 64
#define MCDIM 128
#define GSUM_REP 32   // gsum replication factor (atomic decontention)

// bf16 LDS strides (elements). Row stride in dwords must be == 4 (mod 8) so
// the 16-row A-fragment ds_read_b128 pattern lands 2 lanes/bank (free, m136).
#define XS1 168       // folded edge_input, K = 132 padded -> 160 (84 dw % 8 == 4)
#define HS  136       // hidden layers, K=128                (68 dw % 8 == 4)
#define UST 264       // update_input, K=256                (132 dw % 8 == 4)

typedef __attribute__((ext_vector_type(8))) short short8;
typedef __attribute__((ext_vector_type(4))) float floatx4;
typedef __attribute__((ext_vector_type(2))) float f32x2;

// A&S 7.1.27 erf (abs err 5e-4) gelu, scalar form (used in small kernels).
__device__ __forceinline__ float gelu_fast(float x) {
    float z = fabsf(x) * 0.70710678f;
    float w = fmaf(z, fmaf(z, fmaf(z, fmaf(z, 0.078108f, 0.000972f),
                                   0.230389f), 0.278393f), 1.0f);
    float w2 = w * w;
    float r = __builtin_amdgcn_rcpf(w2 * w2);
    float m = 0.5f * fabsf(x);
    return fmaf(-m, r, fmaf(0.5f, x, m));
}

// Packed-pair gelu: identical per-element math; float2 vector arithmetic lets
// LLVM emit dual-issue v_pk_{mul,add,fma}_f32. rcp stays scalar.
__device__ __forceinline__ f32x2 gelu_pk(f32x2 x) {
    f32x2 ax = __builtin_elementwise_abs(x);
    f32x2 z = ax * 0.70710678f;
    f32x2 w = z * (z * (z * (z * 0.078108f + 0.000972f) + 0.230389f)
                   + 0.278393f) + 1.0f;
    f32x2 w2 = w * w;
    f32x2 w4 = w2 * w2;
    f32x2 r;
    r.x = __builtin_amdgcn_rcpf(w4.x);
    r.y = __builtin_amdgcn_rcpf(w4.y);
    f32x2 m = 0.5f * ax;
    return 0.5f * x + m - m * r;
}

__device__ __forceinline__ unsigned short f2bf(float f) {  // RNE fp32->bf16
    unsigned int u = __float_as_uint(f);
    unsigned int r = u + 0x7fffu + ((u >> 16) & 1u);
    return (unsigned short)(r >> 16);
}
__device__ __forceinline__ float bf2f(unsigned int lo16) {
    return __uint_as_float(lo16 << 16);
}
// packed 2x fp32 -> bf16 pair (v_cvt_pk_bf16_f32 on gfx950)
__device__ __forceinline__ unsigned int f2bf2(float lo, float hi) {
    __hip_bfloat162 v = __float22bfloat162_rn(make_float2(lo, hi));
    union { __hip_bfloat162 b; unsigned int u; } cv;
    cv.b = v;
    return cv.u;
}
__device__ __forceinline__ ushort4 pack4(float4 v) {
    ushort4 r;
    r.x = f2bf(v.x); r.y = f2bf(v.y); r.z = f2bf(v.z); r.w = f2bf(v.w);
    return r;
}

// ---------------------------------------------------------------------------
// Weight fragment pre-swizzle. B-fragment for 16x16x32: lane l holds
// B[k = k0 + (l>>4)*8 + j][n = 16*ct + (l&15)], j=0..7 -> contiguous 16B/lane.
// ew1 is FOLDED: k<64 -> Wi+Wd ; 64..127 -> Wj-Wd ; 128..131 -> geo ; pad 160.
// Also zero-inits deg_int/gsum replicas.
// ---------------------------------------------------------------------------
#define F1_OFF 0               // folded ew1: 5 chunks (K=160), N=128
#define F2_OFF (5 * 4096)      // ew2: 4
#define F3_OFF (9 * 4096)      // ew3: 4
#define FG_OFF (13 * 4096)     // gw1: 4
#define FU1_OFF (17 * 4096)    // uw1: 8 (K=256)
#define FU2_OFF (25 * 4096)    // uw2: 4
#define FU3_OFF (29 * 4096)    // uw3: 4 chunks x 2048 (N=64)
#define FRAG_TOTAL (29 * 4096 + 4 * 2048)   // 126976 ushorts

__global__ __launch_bounds__(256) void prep_frags(
    const float* __restrict__ ew1, const float* __restrict__ ew2,
    const float* __restrict__ ew3, const float* __restrict__ gw1,
    const float* __restrict__ uw1, const float* __restrict__ uw2,
    const float* __restrict__ uw3, unsigned short* __restrict__ frags,
    int* __restrict__ deg_int, float* __restrict__ gsum) {
    int idx = blockIdx.x * 256 + threadIdx.x;
    if (idx < N_NODES) deg_int[idx] = 0;
    if (idx < GSUM_REP * 64) gsum[idx] = 0.0f;
    if (idx >= FRAG_TOTAL) return;
    if (idx < F2_OFF) {  // folded ew1
        int chunk = idx >> 12;
        int rem = idx & 4095;
        int ct = rem >> 9;
        int lane = (rem >> 3) & 63;
        int j = rem & 7;
        int k = chunk * 32 + (lane >> 4) * 8 + j;
        int n = ct * 16 + (lane & 15);
        float v;
        if (k < 64)       v = ew1[k * 128 + n] + ew1[(128 + k) * 128 + n];
        else if (k < 128) v = ew1[k * 128 + n] - ew1[(64 + k) * 128 + n];
        else if (k < 132) v = ew1[(192 + k - 128) * 128 + n];
        else              v = 0.0f;
        frags[idx] = f2bf(v);
    } else if (idx < FU3_OFF) {
        int chunk = idx >> 12;
        int rem = idx & 4095;
        int ct = rem >> 9;
        int lane = (rem >> 3) & 63;
        int j = rem & 7;
        const float* W; int kbase;
        if (chunk < 9)       { W = ew2; kbase = (chunk - 5) * 32; }
        else if (chunk < 13) { W = ew3; kbase = (chunk - 9) * 32; }
        else if (chunk < 17) { W = gw1; kbase = (chunk - 13) * 32; }
        else if (chunk < 25) { W = uw1; kbase = (chunk - 17) * 32; }
        else                 { W = uw2; kbase = (chunk - 25) * 32; }
        int k = kbase + (lane >> 4) * 8 + j;
        int n = ct * 16 + (lane & 15);
        frags[idx] = f2bf(W[k * 128 + n]);
    } else {  // uw3 [128][64]
        int rem = idx - FU3_OFF;
        int chunk = rem >> 11;
        int r = rem & 2047;
        int ct = r >> 9;
        int lane = (r >> 3) & 63;
        int j = r & 7;
        int k = chunk * 32 + (lane >> 4) * 8 + j;
        int n = ct * 16 + (lane & 15);
        frags[idx] = f2bf(uw3[k * 64 + n]);
    }
}

// ---------------------------------------------------------------------------
// MFMA helpers. acc init = column-broadcast bias.
// ---------------------------------------------------------------------------
template <int NCT>
__device__ __forceinline__ void bias_init(floatx4* acc,
                                          const float* __restrict__ bias, int lane) {
    int c = lane & 15;
#pragma unroll
    for (int ct = 0; ct < NCT; ct++) {
        float b = bias[ct * 16 + c];
        acc[ct][0] = b; acc[ct][1] = b; acc[ct][2] = b; acc[ct][3] = b;
    }
}

template <int NCH, int NCT>
__device__ __forceinline__ void mfma_layer(const unsigned short* Xl, int xs,
                                           const unsigned short* __restrict__ F,
                                           int lane, floatx4* acc) {
    int q = lane >> 4, c = lane & 15;
    const unsigned short* xrow = Xl + c * xs + q * 8;
    for (int k0 = 0; k0 < NCH; k0++) {
        short8 a = *(const short8*)(xrow + k0 * 32);
#pragma unroll
        for (int ct = 0; ct < NCT; ct++) {
            short8 b = *(const short8*)(F + ((k0 * NCT + ct) * 64 + lane) * 8);
            acc[ct] = __builtin_amdgcn_mfma_f32_16x16x32_bf16(a, b, acc[ct], 0, 0, 0);
        }
    }
}

// (opt) packed gelu + packed-bf16 store into an A-layout LDS tile.
// C layout: value (ct,i) at row (lane>>4)*4+i, col 16*ct+(lane&15).
template <bool GELU, int NCT>
__device__ __forceinline__ void epilogue_store(floatx4* acc,
                                               unsigned short* dst, int xs, int lane) {
    int q = lane >> 4, c = lane & 15;
    unsigned short* base = dst + (q * 4) * xs + c;
#pragma unroll
    for (int ct = 0; ct < NCT; ct++) {
        f32x2 v01 = {acc[ct][0], acc[ct][1]};
        f32x2 v23 = {acc[ct][2], acc[ct][3]};
        if (GELU) { v01 = gelu_pk(v01); v23 = gelu_pk(v23); }
        unsigned int p01 = f2bf2(v01.x, v01.y), p23 = f2bf2(v23.x, v23.y);
        unsigned short* p = base + ct * 16;
        p[0]      = (unsigned short)p01;
        p[xs]     = (unsigned short)(p01 >> 16);
        p[2 * xs] = (unsigned short)p23;
        p[3 * xs] = (unsigned short)(p23 >> 16);
    }
}

// ---------------------------------------------------------------------------
// LayerNorm (bf16 out) + global-mean partials (replicated atomics)
// + flow_dir normalize + degree
// ---------------------------------------------------------------------------
__global__ __launch_bounds__(256) void ln_count_kernel(
    const float* __restrict__ h, const float* __restrict__ ln_g,
    const float* __restrict__ ln_b, const float* __restrict__ flow_dir,
    const int* __restrict__ eidx, unsigned short* __restrict__ featb,
    float* __restrict__ gsum, float* __restrict__ u_out,
    int* __restrict__ deg_int) {
    int t = threadIdx.x;
    int ln = t >> 6;
    int c = t & 63;
    int n = blockIdx.x * 4 + ln;

    float x = h[n * CDIM + c];
    float s = x;
#pragma unroll
    for (int off = 32; off > 0; off >>= 1) s += __shfl_xor(s, off, 64);
    float mu = s * (1.0f / 64.0f);
    float d = x - mu;
    float v = d * d;
#pragma unroll
    for (int off = 32; off > 0; off >>= 1) v += __shfl_xor(v, off, 64);
    float rs = 1.0f / sqrtf(v * (1.0f / 64.0f) + 1e-5f);
    float f = d * rs * ln_g[c] + ln_b[c];
    featb[n * CDIM + c] = f2bf(f);

    __shared__ float fs[4][64];
    fs[ln][c] = f;
    __syncthreads();   // cross-wave reduction below
    if (t < 64) {
        float p = fs[0][t] + fs[1][t] + fs[2][t] + fs[3][t];
        atomicAdd(&gsum[(blockIdx.x & (GSUM_REP - 1)) * 64 + t], p);
        int e = blockIdx.x * 64 + t;           // 12500*64 == N_EDGES
        atomicAdd(&deg_int[eidx[e]], 1);
    }
    if (blockIdx.x == 0 && t == 0) {
        float ux = flow_dir[0], uy = flow_dir[1], uz = flow_dir[2];
        float nrm = sqrtf(ux * ux + uy * uy + uz * uz) + 1e-8f;
        u_out[0] = ux / nrm;
        u_out[1] = uy / nrm;
        u_out[2] = uz / nrm;
    }
}

// ---------------------------------------------------------------------------
// Merged mid kernel: block 0 = exclusive prefix scan; block 1 = global MLP
// (first reducing the gsum replicas).
// ---------------------------------------------------------------------------
__global__ __launch_bounds__(1024) void mid_kernel(
    const int* __restrict__ deg_int, int* __restrict__ rowstart,
    int* __restrict__ cursor,
    const float* __restrict__ gsum,
    const float* __restrict__ glw1, const float* __restrict__ glb1,
    const float* __restrict__ glw2, const float* __restrict__ glb2,
    const float* __restrict__ glw3, const float* __restrict__ glb3,
    const float* __restrict__ res_scale,
    unsigned short* __restrict__ gctxb, float* __restrict__ tres) {
    int t = threadIdx.x;
    if (blockIdx.x == 0) {
        __shared__ int wsum[16];
        __shared__ int run;
        int wid = t >> 6, lane = t & 63;
        int4 vs[13];
#pragma unroll
        for (int chunk = 0; chunk < 13; chunk++) {
            int base = chunk * 4096 + t * 4;
            int4 v = {0, 0, 0, 0};
            if (base + 3 < N_NODES) {
                v = *(const int4*)(deg_int + base);
            } else {
                if (base < N_NODES) v.x = deg_int[base];
                if (base + 1 < N_NODES) v.y = deg_int[base + 1];
                if (base + 2 < N_NODES) v.z = deg_int[base + 2];
                if (base + 3 < N_NODES) v.w = deg_int[base + 3];
            }
            vs[chunk] = v;
        }
        if (t == 0) run = 0;
        __syncthreads();
#pragma unroll
        for (int chunk = 0; chunk < 13; chunk++) {
            int base = chunk * 4096 + t * 4;
            int4 v = vs[chunk];
            int s1 = v.x, s2 = s1 + v.y, s3 = s2 + v.z, s4 = s3 + v.w;
            int x = s4;
#pragma unroll
            for (int off = 1; off < 64; off <<= 1) {
                int y = __shfl_up(x, off, 64);
                if (lane >= off) x += y;
            }
            if (lane == 63) wsum[wid] = x;
            __syncthreads();
            if (t < 16) {
                int sv = wsum[t];
#pragma unroll
                for (int off = 1; off < 16; off <<= 1) {
                    int y = __shfl_up(sv, off, 16);
                    if (t >= off) sv += y;
                }
                wsum[t] = sv;
            }
            __syncthreads();
            int run_l = run;
            int wpre = (wid == 0) ? 0 : wsum[wid - 1];
            int toff = run_l + wpre + (x - s4);
            int e0 = toff, e1 = toff + s1, e2 = toff + s2, e3 = toff + s3;
            if (base <= N_NODES) rowstart[base] = e0;
            if (base + 1 <= N_NODES) rowstart[base + 1] = e1;
            if (base + 2 <= N_NODES) rowstart[base + 2] = e2;
            if (base + 3 <= N_NODES) rowstart[base + 3] = e3;
            if (base < N_NODES) cursor[base] = e0;
            if (base + 1 < N_NODES) cursor[base + 1] = e1;
            if (base + 2 < N_NODES) cursor[base + 2] = e2;
            if (base + 3 < N_NODES) cursor[base + 3] = e3;
            __syncthreads();
            if (t == 0) run = run_l + wsum[15];
            __syncthreads();
        }
    } else {
        __shared__ float a[64], b[64];
        float s = 0.0f;
        if (t < 64) {
            float acc = 0.0f;
            for (int r = 0; r < GSUM_REP; r++) acc += gsum[r * 64 + t];
            a[t] = acc * (1.0f / (float)N_NODES);
        }
        __syncthreads();
        if (t < 64) {
            s = glb1[t];
            for (int k = 0; k < 64; k++) s += a[k] * glw1[k * 64 + t];
            b[t] = gelu_fast(s);
        }
        __syncthreads();
        if (t < 64) {
            s = glb2[t];
            for (int k = 0; k < 64; k++) s += b[k] * glw2[k * 64 + t];
        }
        __syncthreads();
        if (t < 64) a[t] = gelu_fast(s);
        __syncthreads();
        if (t < 64) {
            s = glb3[t];
            for (int k = 0; k < 64; k++) s += a[k] * glw3[k * 64 + t];
            gctxb[t] = f2bf(s);
        }
        if (t == 0) *tres = tanhf(res_scale[0]);
    }
}

// ---------------------------------------------------------------------------
// Fused MFMA edge pipeline: 64 edges/block, 4 waves x 16 rows.
// SINGLE LDS buffer: each wave's 16xXS1 slice hosts, in sequence,
// edge_input -> H1 -> H2 -> H3 -> gated msg (all reads of stage k complete
// before stage k+1's writes, in-wave; compiler enforces LDS RAW order).
// LDS 39.9 -> 22.3 KB => 7 blocks/CU (was 4): latency-bound fix via occupancy.
// ---------------------------------------------------------------------------
struct SmemE {
    unsigned short x1[64 * XS1];   // 21504 B, all pipeline stages live here
    float gate[64];
    int pos[64];
    int rows[64];
};

__global__ __launch_bounds__(256, 7) void edge_kernel(
    const float* __restrict__ coords, const int* __restrict__ eidx,
    const unsigned short* __restrict__ featb, const float* __restrict__ u,
    const unsigned short* __restrict__ frags,
    const float* __restrict__ eb1, const float* __restrict__ eb2,
    const float* __restrict__ eb3,
    const float* __restrict__ gb1, const float* __restrict__ gw2,
    const float* __restrict__ gb2,
    int* __restrict__ cursor, unsigned short* __restrict__ msg,
    float* __restrict__ agg, int use_msg) {
    __shared__ SmemE sm;
    int t = threadIdx.x;
    int wv = t >> 6;
    int lane = t & 63;
    int e0 = blockIdx.x * 64;
    unsigned short* slice = sm.x1 + wv * 16 * XS1;   // wave-private

    {   // stage folded edge_input (bf16 copies, no cvt): 4 threads/edge
        int le = t >> 2, sub = t & 3;
        int e = e0 + le;
        int row = eidx[e];
        int col = eidx[N_EDGES + e];
        const uint4* fi4 = (const uint4*)(featb + (long)row * CDIM);
        const uint4* fj4 = (const uint4*)(featb + (long)col * CDIM);
        unsigned short* xr = sm.x1 + le * XS1;
        *(uint4*)(xr + sub * 16) = fi4[sub * 2];
        *(uint4*)(xr + sub * 16 + 8) = fi4[sub * 2 + 1];
        *(uint4*)(xr + 64 + sub * 16) = fj4[sub * 2];
        *(uint4*)(xr + 64 + sub * 16 + 8) = fj4[sub * 2 + 1];
        ushort4 z = {0, 0, 0, 0};
        if (sub == 0) {
            sm.rows[le] = row;
            sm.pos[le] = atomicAdd(&cursor[row], 1);  // cursor pre-seeded = rowstart
            float xix = coords[row * 3], xiy = coords[row * 3 + 1], xiz = coords[row * 3 + 2];
            float xjx = coords[col * 3], xjy = coords[col * 3 + 1], xjz = coords[col * 3 + 2];
            float rx = xix - xjx, ry = xiy - xjy, rz = xiz - xjz;
            float ux = u[0], uy = u[1], uz = u[2];
            float4 sc;
            sc.x = rx * rx + ry * ry + rz * rz;
            sc.y = xix * ux + xiy * uy + xiz * uz;
            sc.z = xjx * ux + xjy * uy + xjz * uz;
            sc.w = rx * ux + ry * uy + rz * uz;
            *(ushort4*)(xr + 128) = pack4(sc);
        } else if (sub == 1) {
            *(ushort4*)(xr + 132) = z; *(ushort4*)(xr + 136) = z; *(ushort4*)(xr + 140) = z;
        } else if (sub == 2) {
            *(ushort4*)(xr + 144) = z; *(ushort4*)(xr + 148) = z;
        } else {
            *(ushort4*)(xr + 152) = z; *(ushort4*)(xr + 156) = z;
        }
    }
    __syncthreads();

    floatx4 acc[8];

    // L1 (folded, K=160): reads slice @XS1, writes H1 into slice @HS
    bias_init<8>(acc, eb1, lane);
    mfma_layer<5, 8>(slice, XS1, frags + F1_OFF, lane, acc);
    epilogue_store<true, 8>(acc, slice, HS, lane);
    __syncthreads();

    // L2: H1 -> H2 (same slice; in-wave sequential)
    bias_init<8>(acc, eb2, lane);
    mfma_layer<4, 8>(slice, HS, frags + F2_OFF, lane, acc);
    epilogue_store<true, 8>(acc, slice, HS, lane);
    __syncthreads();

    // L3 -> h3 fp32 in regs + bf16 H3 back into slice for the gate GEMM
    floatx4 h3[8];
    bias_init<8>(h3, eb3, lane);
    mfma_layer<4, 8>(slice, HS, frags + F3_OFF, lane, h3);
    epilogue_store<false, 8>(h3, slice, HS, lane);
    __syncthreads();

    // Gate
    bias_init<8>(acc, gb1, lane);
    mfma_layer<4, 8>(slice, HS, frags + FG_OFF, lane, acc);
    {
        int q = lane >> 4, c = lane & 15;
        f32x2 p01 = {0.0f, 0.0f}, p23 = {0.0f, 0.0f};
#pragma unroll
        for (int ct = 0; ct < 8; ct++) {
            float w2 = gw2[ct * 16 + c];
            f32x2 g01 = gelu_pk((f32x2){acc[ct][0], acc[ct][1]});
            f32x2 g23 = gelu_pk((f32x2){acc[ct][2], acc[ct][3]});
            p01 += g01 * w2;
            p23 += g23 * w2;
        }
        float p[4] = {p01.x, p01.y, p23.x, p23.y};
#pragma unroll
        for (int i = 0; i < 4; i++) {
#pragma unroll
            for (int mask = 1; mask < 16; mask <<= 1) p[i] += __shfl_xor(p[i], mask, 64);
        }
        if (c == 0) {
            float gb = gb2[0];
#pragma unroll
            for (int i = 0; i < 4; i++) {
                float z = p[i] + gb;
                sm.gate[wv * 16 + q * 4 + i] = 1.0f / (1.0f + __expf(-z));
            }
        }
    }
    __syncthreads();

    if (use_msg) {
        {   // scaled bf16 message into slice (C->row layout)
            int q = lane >> 4, c = lane & 15;
            unsigned short* base = slice + (q * 4) * HS + c;
            float gv[4];
#pragma unroll
            for (int i = 0; i < 4; i++) gv[i] = sm.gate[wv * 16 + q * 4 + i];
#pragma unroll
            for (int ct = 0; ct < 8; ct++) {
                unsigned int p01 = f2bf2(h3[ct][0] * gv[0], h3[ct][1] * gv[1]);
                unsigned int p23 = f2bf2(h3[ct][2] * gv[2], h3[ct][3] * gv[3]);
                unsigned short* p = base + ct * 16;
                p[0] = (unsigned short)p01;
                p[HS] = (unsigned short)(p01 >> 16);
                p[2 * HS] = (unsigned short)p23;
                p[3 * HS] = (unsigned short)(p23 >> 16);
            }
        }
        __syncthreads();
        {   // coalesced 256B-row stream to msg[pos[e]] (wave-private rows)
            int le = t >> 2, sub = t & 3;
            long base = (long)sm.pos[le] * MCDIM;
            const unsigned short* src = sm.x1 + (le >> 4) * 16 * XS1 + (le & 15) * HS;
#pragma unroll
            for (int m = 0; m < 4; m++) {
                int off = m * 32 + sub * 8;
                *(short8*)(msg + base + off) = *(const short8*)(src + off);
            }
        }
    } else {
        int q = lane >> 4, c = lane & 15;
#pragma unroll
        for (int i = 0; i < 4; i++) {
            int e = wv * 16 + q * 4 + i;
            int row = sm.rows[e];
            float g = sm.gate[e];
            float* agr = agg + (long)row * MCDIM;
#pragma unroll
            for (int ct = 0; ct < 8; ct++)
                atomicAdd(agr + ct * 16 + c, g * h3[ct][i]);
        }
    }
}

// ---------------------------------------------------------------------------
// Gather: one wave per node; lane loads uint2 spanning TWO msg rows/iter.
// ---------------------------------------------------------------------------
__global__ __launch_bounds__(256) void gather_kernel(
    const int* __restrict__ rowstart, const unsigned short* __restrict__ msg,
    const float* __restrict__ agg, int use_msg,
    unsigned short* __restrict__ aggb) {
    int wv = threadIdx.x >> 6, lane = threadIdx.x & 63;
    int n = blockIdx.x * 4 + wv;
    if (n >= N_NODES) return;
    int rs = rowstart[n], re = rowstart[n + 1];
    int deg = re - rs;
    float a0 = 0.0f, a1 = 0.0f, a2 = 0.0f, a3 = 0.0f;
    if (use_msg) {
        const unsigned short* base = msg + (long)rs * MCDIM;
        int pairs = deg >> 1;
        for (int i = 0; i < pairs; i++) {
            uint2 v = *(const uint2*)(base + i * 256 + lane * 4);
            a0 += bf2f(v.x & 0xffffu); a1 += bf2f(v.x >> 16);
            a2 += bf2f(v.y & 0xffffu); a3 += bf2f(v.y >> 16);
        }
        if ((deg & 1) && lane < 32) {
            uint2 v = *(const uint2*)(base + (deg - 1) * MCDIM + lane * 4);
            a0 += bf2f(v.x & 0xffffu); a1 += bf2f(v.x >> 16);
            a2 += bf2f(v.y & 0xffffu); a3 += bf2f(v.y >> 16);
        }
        a0 += __shfl_xor(a0, 32, 64);
        a1 += __shfl_xor(a1, 32, 64);
        a2 += __shfl_xor(a2, 32, 64);
        a3 += __shfl_xor(a3, 32, 64);
    } else if (lane < 32) {
        const float4 v = *(const float4*)(agg + (long)n * MCDIM + lane * 4);
        a0 = v.x; a1 = v.y; a2 = v.z; a3 = v.w;
    }
    if (lane < 32) {
        float inv = 1.0f / fmaxf((float)deg, 1.0f);
        uint2 o;
        o.x = f2bf2(a0 * inv, a1 * inv);
        o.y = f2bf2(a2 * inv, a3 * inv);
        *(uint2*)(aggb + (long)n * MCDIM + lane * 4) = o;
    }
}

// ---------------------------------------------------------------------------
// MFMA node update: single-buffer slices (same trick). 64 nodes/block,
// LDS 51 -> 33.8 KB => 4 blocks/CU (was 3).
// ---------------------------------------------------------------------------
struct SmemU {
    unsigned short ui[64 * UST];   // 33792 B, all stages live here
};

__global__ __launch_bounds__(256, 4) void update_kernel(
    const unsigned short* __restrict__ featb, const unsigned short* __restrict__ aggb,
    const unsigned short* __restrict__ gctxb, const float* __restrict__ tres,
    const unsigned short* __restrict__ frags,
    const float* __restrict__ ub1, const float* __restrict__ ub2,
    const float* __restrict__ ub3,
    float* __restrict__ out) {
    __shared__ SmemU sm;
    int t = threadIdx.x;
    int wv = t >> 6;
    int lane = t & 63;
    int n0 = blockIdx.x * 64;
    unsigned short* slice = sm.ui + wv * 16 * UST;   // wave-private

    {   // stage [feat | agg | gctx] (all bf16 copies): 4 threads/node
        int ln = t >> 2, sub = t & 3;
        int n = n0 + ln;
        unsigned short* ur = sm.ui + ln * UST;
        if (n < N_NODES) {
            const uint4* f4 = (const uint4*)(featb + (long)n * CDIM);
            *(uint4*)(ur + sub * 16) = f4[sub * 2];
            *(uint4*)(ur + sub * 16 + 8) = f4[sub * 2 + 1];
            const uint4* a4 = (const uint4*)(aggb + (long)n * MCDIM);
            *(uint4*)(ur + 64 + sub * 32) = a4[sub * 4];
            *(uint4*)(ur + 64 + sub * 32 + 8) = a4[sub * 4 + 1];
            *(uint4*)(ur + 64 + sub * 32 + 16) = a4[sub * 4 + 2];
            *(uint4*)(ur + 64 + sub * 32 + 24) = a4[sub * 4 + 3];
            const uint4* g4 = (const uint4*)gctxb;
            *(uint4*)(ur + 192 + sub * 16) = g4[sub * 2];
            *(uint4*)(ur + 192 + sub * 16 + 8) = g4[sub * 2 + 1];
        } else {
            uint4 z = {0, 0, 0, 0};
#pragma unroll
            for (int m = 0; m < 8; m++) *(uint4*)(ur + sub * 64 + m * 8) = z;
        }
    }
    __syncthreads();

    floatx4 acc[8];
    bias_init<8>(acc, ub1, lane);
    mfma_layer<8, 8>(slice, UST, frags + FU1_OFF, lane, acc);
    epilogue_store<true, 8>(acc, slice, HS, lane);
    __syncthreads();

    bias_init<8>(acc, ub2, lane);
    mfma_layer<4, 8>(slice, HS, frags + FU2_OFF, lane, acc);
    epilogue_store<true, 8>(acc, slice, HS, lane);
    __syncthreads();

    floatx4 acc3[4];
    bias_init<4>(acc3, ub3, lane);
    mfma_layer<4, 4>(slice, HS, frags + FU3_OFF, lane, acc3);
    {
        int q = lane >> 4, c = lane & 15;
        float tr = *tres;
#pragma unroll
        for (int ct = 0; ct < 4; ct++) {
#pragma unroll
            for (int i = 0; i < 4; i++) {
                int n = n0 + wv * 16 + q * 4 + i;
                if (n < N_NODES) out[(long)n * CDIM + ct * 16 + c] = acc3[ct][i] * tr;
            }
        }
    }
}

// ---------------------------------------------------------------------------
extern "C" void kernel_launch(void* const* d_in, const int* in_sizes, int n_in,
                              void* d_out, int out_size, void* d_ws, size_t ws_size,
                              hipStream_t stream) {
    const float* coords = (const float*)d_in[0];
    const float* h = (const float*)d_in[1];
    const float* flow = (const float*)d_in[2];
    const int* eidx = (const int*)d_in[3];
    const float* ln_g = (const float*)d_in[4];
    const float* ln_b = (const float*)d_in[5];
    const float* ew1 = (const float*)d_in[6];
    const float* eb1 = (const float*)d_in[7];
    const float* ew2 = (const float*)d_in[8];
    const float* eb2 = (const float*)d_in[9];
    const float* ew3 = (const float*)d_in[10];
    const float* eb3 = (const float*)d_in[11];
    const float* gw1 = (const float*)d_in[12];
    const float* gb1 = (const float*)d_in[13];
    const float* gw2 = (const float*)d_in[14];
    const float* gb2 = (const float*)d_in[15];
    const float* glw1 = (const float*)d_in[16];
    const float* glb1 = (const float*)d_in[17];
    const float* glw2 = (const float*)d_in[18];
    const float* glb2 = (const float*)d_in[19];
    const float* glw3 = (const float*)d_in[20];
    const float* glb3 = (const float*)d_in[21];
    const float* uw1 = (const float*)d_in[22];
    const float* ub1 = (const float*)d_in[23];
    const float* uw2 = (const float*)d_in[24];
    const float* ub2 = (const float*)d_in[25];
    const float* uw3 = (const float*)d_in[26];
    const float* ub3 = (const float*)d_in[27];
    const float* res = (const float*)d_in[28];

    // ---- workspace carve-up ----
    char* base = (char*)d_ws;
    unsigned short* frags = (unsigned short*)base;                 // FRAG_TOTAL us
    unsigned short* featb = (unsigned short*)(base + FRAG_TOTAL * 2); // N*64 us
    unsigned short* aggb = featb + (size_t)N_NODES * CDIM;         // N*128 us
    unsigned short* gctxb = aggb + (size_t)N_NODES * MCDIM;        // 64 us
    float* gsum = (float*)(gctxb + 64);                            // 32*64
    float* u = gsum + GSUM_REP * 64;                               // 4
    float* tres = u + 4;                                           // 1
    int* rowstart = (int*)(tres + 1);                              // N+1
    int* cursor = rowstart + (N_NODES + 1);                        // N
    int* deg_int = cursor + N_NODES;                               // N
    char* tail = (char*)(deg_int + N_NODES);
    tail = (char*)(((uintptr_t)tail + 255) & ~(uintptr_t)255);
    size_t head_bytes = (size_t)(tail - base);
    size_t msg_bytes = (size_t)N_EDGES * MCDIM * 2;                // 204.8 MB bf16
    int use_msg = (ws_size >= head_bytes + msg_bytes) ? 1 : 0;
    unsigned short* msg = (unsigned short*)tail;                   // CSR slots
    float* agg = (float*)tail;                                     // fallback

    if (!use_msg)
        hipMemsetAsync(agg, 0, (size_t)N_NODES * MCDIM * sizeof(float), stream);

    prep_frags<<<FRAG_TOTAL / 256, 256, 0, stream>>>(ew1, ew2, ew3, gw1,
                                                     uw1, uw2, uw3, frags,
                                                     deg_int, gsum);
    ln_count_kernel<<<N_NODES / 4, 256, 0, stream>>>(h, ln_g, ln_b, flow, eidx,
                                                     featb, gsum, u, deg_int);
    mid_kernel<<<2, 1024, 0, stream>>>(deg_int, rowstart, cursor, gsum,
                                       glw1, glb1, glw2, glb2, glw3, glb3,
                                       res, gctxb, tres);
    edge_kernel<<<N_EDGES / 64, 256, 0, stream>>>(coords, eidx, featb, u, frags,
                                                  eb1, eb2, eb3, gb1, gw2, gb2,
                                                  cursor, msg, agg, use_msg);
    gather_kernel<<<(N_NODES + 3) / 4, 256, 0, stream>>>(rowstart, msg, agg,
                                                         use_msg, aggb);
    update_kernel<<<(N_NODES + 63) / 64, 256, 0, stream>>>(featb, aggb, gctxb,
                                                           tres, frags,
                                                           ub1, ub2, ub3,
                                                           (float*)d_out);
}

// Round 10
// 608.989 us; speedup vs baseline: 1.0633x; 1.0633x over previous
//
#include <hip/hip_runtime.h>
#include <hip/hip_bf16.h>
#include <math.h>

#define N_NODES 50000
#define N_EDGES 800000
#define CDIM 64
#define MCDIM 128
#define GSUM_REP 32   // gsum replication factor (atomic decontention)

// bf16 LDS strides (elements). Row stride in dwords must be == 4 (mod 8) so
// the 16-row A-fragment ds_read_b128 pattern lands 2 lanes/bank (free, m136).
#define XS1 168       // folded edge_input, K = 132 padded -> 160 (84 dw % 8 == 4)
#define HS  136       // hidden layers, K=128                (68 dw % 8 == 4)
#define UST 264       // update_input, K=256                (132 dw % 8 == 4)

typedef __attribute__((ext_vector_type(8))) short short8;
typedef __attribute__((ext_vector_type(4))) float floatx4;
typedef __attribute__((ext_vector_type(2))) float f32x2;

// A&S 7.1.27 erf (abs err 5e-4) gelu, scalar form (used in small kernels).
__device__ __forceinline__ float gelu_fast(float x) {
    float z = fabsf(x) * 0.70710678f;
    float w = fmaf(z, fmaf(z, fmaf(z, fmaf(z, 0.078108f, 0.000972f),
                                   0.230389f), 0.278393f), 1.0f);
    float w2 = w * w;
    float r = __builtin_amdgcn_rcpf(w2 * w2);
    float m = 0.5f * fabsf(x);
    return fmaf(-m, r, fmaf(0.5f, x, m));
}

// Packed-pair gelu: identical per-element math; float2 vector arithmetic lets
// LLVM emit dual-issue v_pk_{mul,add,fma}_f32. rcp stays scalar.
__device__ __forceinline__ f32x2 gelu_pk(f32x2 x) {
    f32x2 ax = __builtin_elementwise_abs(x);
    f32x2 z = ax * 0.70710678f;
    f32x2 w = z * (z * (z * (z * 0.078108f + 0.000972f) + 0.230389f)
                   + 0.278393f) + 1.0f;
    f32x2 w2 = w * w;
    f32x2 w4 = w2 * w2;
    f32x2 r;
    r.x = __builtin_amdgcn_rcpf(w4.x);
    r.y = __builtin_amdgcn_rcpf(w4.y);
    f32x2 m = 0.5f * ax;
    return 0.5f * x + m - m * r;
}

__device__ __forceinline__ unsigned short f2bf(float f) {  // RNE fp32->bf16
    unsigned int u = __float_as_uint(f);
    unsigned int r = u + 0x7fffu + ((u >> 16) & 1u);
    return (unsigned short)(r >> 16);
}
__device__ __forceinline__ float bf2f(unsigned int lo16) {
    return __uint_as_float(lo16 << 16);
}
// packed 2x fp32 -> bf16 pair (v_cvt_pk_bf16_f32 on gfx950)
__device__ __forceinline__ unsigned int f2bf2(float lo, float hi) {
    __hip_bfloat162 v = __float22bfloat162_rn(make_float2(lo, hi));
    union { __hip_bfloat162 b; unsigned int u; } cv;
    cv.b = v;
    return cv.u;
}
__device__ __forceinline__ ushort4 pack4(float4 v) {
    ushort4 r;
    r.x = f2bf(v.x); r.y = f2bf(v.y); r.z = f2bf(v.z); r.w = f2bf(v.w);
    return r;
}
// scale 2 packed bf16 by float g, repack
__device__ __forceinline__ unsigned int bfscale2(unsigned int w, float g) {
    return f2bf2(bf2f(w & 0xffffu) * g, bf2f(w >> 16) * g);
}

// ---------------------------------------------------------------------------
// Weight fragment pre-swizzle. B-fragment for 16x16x32: lane l holds
// B[k = k0 + (l>>4)*8 + j][n = 16*ct + (l&15)], j=0..7 -> contiguous 16B/lane.
// ew1 is FOLDED: k<64 -> Wi+Wd ; 64..127 -> Wj-Wd ; 128..131 -> geo ; pad 160.
// Also zero-inits deg_int/gsum replicas.
// ---------------------------------------------------------------------------
#define F1_OFF 0               // folded ew1: 5 chunks (K=160), N=128
#define F2_OFF (5 * 4096)      // ew2: 4
#define F3_OFF (9 * 4096)      // ew3: 4
#define FG_OFF (13 * 4096)     // gw1: 4
#define FU1_OFF (17 * 4096)    // uw1: 8 (K=256)
#define FU2_OFF (25 * 4096)    // uw2: 4
#define FU3_OFF (29 * 4096)    // uw3: 4 chunks x 2048 (N=64)
#define FRAG_TOTAL (29 * 4096 + 4 * 2048)   // 126976 ushorts

__global__ __launch_bounds__(256) void prep_frags(
    const float* __restrict__ ew1, const float* __restrict__ ew2,
    const float* __restrict__ ew3, const float* __restrict__ gw1,
    const float* __restrict__ uw1, const float* __restrict__ uw2,
    const float* __restrict__ uw3, unsigned short* __restrict__ frags,
    int* __restrict__ deg_int, float* __restrict__ gsum) {
    int idx = blockIdx.x * 256 + threadIdx.x;
    if (idx < N_NODES) deg_int[idx] = 0;
    if (idx < GSUM_REP * 64) gsum[idx] = 0.0f;
    if (idx >= FRAG_TOTAL) return;
    if (idx < F2_OFF) {  // folded ew1
        int chunk = idx >> 12;
        int rem = idx & 4095;
        int ct = rem >> 9;
        int lane = (rem >> 3) & 63;
        int j = rem & 7;
        int k = chunk * 32 + (lane >> 4) * 8 + j;
        int n = ct * 16 + (lane & 15);
        float v;
        if (k < 64)       v = ew1[k * 128 + n] + ew1[(128 + k) * 128 + n];
        else if (k < 128) v = ew1[k * 128 + n] - ew1[(64 + k) * 128 + n];
        else if (k < 132) v = ew1[(192 + k - 128) * 128 + n];
        else              v = 0.0f;
        frags[idx] = f2bf(v);
    } else if (idx < FU3_OFF) {
        int chunk = idx >> 12;
        int rem = idx & 4095;
        int ct = rem >> 9;
        int lane = (rem >> 3) & 63;
        int j = rem & 7;
        const float* W; int kbase;
        if (chunk < 9)       { W = ew2; kbase = (chunk - 5) * 32; }
        else if (chunk < 13) { W = ew3; kbase = (chunk - 9) * 32; }
        else if (chunk < 17) { W = gw1; kbase = (chunk - 13) * 32; }
        else if (chunk < 25) { W = uw1; kbase = (chunk - 17) * 32; }
        else                 { W = uw2; kbase = (chunk - 25) * 32; }
        int k = kbase + (lane >> 4) * 8 + j;
        int n = ct * 16 + (lane & 15);
        frags[idx] = f2bf(W[k * 128 + n]);
    } else {  // uw3 [128][64]
        int rem = idx - FU3_OFF;
        int chunk = rem >> 11;
        int r = rem & 2047;
        int ct = r >> 9;
        int lane = (r >> 3) & 63;
        int j = r & 7;
        int k = chunk * 32 + (lane >> 4) * 8 + j;
        int n = ct * 16 + (lane & 15);
        frags[idx] = f2bf(uw3[k * 64 + n]);
    }
}

// ---------------------------------------------------------------------------
// MFMA helpers. acc init = column-broadcast bias.
// ---------------------------------------------------------------------------
template <int NCT>
__device__ __forceinline__ void bias_init(floatx4* acc,
                                          const float* __restrict__ bias, int lane) {
    int c = lane & 15;
#pragma unroll
    for (int ct = 0; ct < NCT; ct++) {
        float b = bias[ct * 16 + c];
        acc[ct][0] = b; acc[ct][1] = b; acc[ct][2] = b; acc[ct][3] = b;
    }
}

template <int NCH, int NCT>
__device__ __forceinline__ void mfma_layer(const unsigned short* Xl, int xs,
                                           const unsigned short* __restrict__ F,
                                           int lane, floatx4* acc) {
    int q = lane >> 4, c = lane & 15;
    const unsigned short* xrow = Xl + c * xs + q * 8;
    for (int k0 = 0; k0 < NCH; k0++) {
        short8 a = *(const short8*)(xrow + k0 * 32);
#pragma unroll
        for (int ct = 0; ct < NCT; ct++) {
            short8 b = *(const short8*)(F + ((k0 * NCT + ct) * 64 + lane) * 8);
            acc[ct] = __builtin_amdgcn_mfma_f32_16x16x32_bf16(a, b, acc[ct], 0, 0, 0);
        }
    }
}

// (opt) packed gelu + packed-bf16 store into an A-layout LDS tile.
// C layout: value (ct,i) at row (lane>>4)*4+i, col 16*ct+(lane&15).
template <bool GELU, int NCT>
__device__ __forceinline__ void epilogue_store(floatx4* acc,
                                               unsigned short* dst, int xs, int lane) {
    int q = lane >> 4, c = lane & 15;
    unsigned short* base = dst + (q * 4) * xs + c;
#pragma unroll
    for (int ct = 0; ct < NCT; ct++) {
        f32x2 v01 = {acc[ct][0], acc[ct][1]};
        f32x2 v23 = {acc[ct][2], acc[ct][3]};
        if (GELU) { v01 = gelu_pk(v01); v23 = gelu_pk(v23); }
        unsigned int p01 = f2bf2(v01.x, v01.y), p23 = f2bf2(v23.x, v23.y);
        unsigned short* p = base + ct * 16;
        p[0]      = (unsigned short)p01;
        p[xs]     = (unsigned short)(p01 >> 16);
        p[2 * xs] = (unsigned short)p23;
        p[3 * xs] = (unsigned short)(p23 >> 16);
    }
}

// ---------------------------------------------------------------------------
// LayerNorm (bf16 out) + global-mean partials (replicated atomics)
// + flow_dir normalize + degree
// ---------------------------------------------------------------------------
__global__ __launch_bounds__(256) void ln_count_kernel(
    const float* __restrict__ h, const float* __restrict__ ln_g,
    const float* __restrict__ ln_b, const float* __restrict__ flow_dir,
    const int* __restrict__ eidx, unsigned short* __restrict__ featb,
    float* __restrict__ gsum, float* __restrict__ u_out,
    int* __restrict__ deg_int) {
    int t = threadIdx.x;
    int ln = t >> 6;
    int c = t & 63;
    int n = blockIdx.x * 4 + ln;

    float x = h[n * CDIM + c];
    float s = x;
#pragma unroll
    for (int off = 32; off > 0; off >>= 1) s += __shfl_xor(s, off, 64);
    float mu = s * (1.0f / 64.0f);
    float d = x - mu;
    float v = d * d;
#pragma unroll
    for (int off = 32; off > 0; off >>= 1) v += __shfl_xor(v, off, 64);
    float rs = 1.0f / sqrtf(v * (1.0f / 64.0f) + 1e-5f);
    float f = d * rs * ln_g[c] + ln_b[c];
    featb[n * CDIM + c] = f2bf(f);

    __shared__ float fs[4][64];
    fs[ln][c] = f;
    __syncthreads();   // cross-wave reduction below
    if (t < 64) {
        float p = fs[0][t] + fs[1][t] + fs[2][t] + fs[3][t];
        atomicAdd(&gsum[(blockIdx.x & (GSUM_REP - 1)) * 64 + t], p);
        int e = blockIdx.x * 64 + t;           // 12500*64 == N_EDGES
        atomicAdd(&deg_int[eidx[e]], 1);
    }
    if (blockIdx.x == 0 && t == 0) {
        float ux = flow_dir[0], uy = flow_dir[1], uz = flow_dir[2];
        float nrm = sqrtf(ux * ux + uy * uy + uz * uz) + 1e-8f;
        u_out[0] = ux / nrm;
        u_out[1] = uy / nrm;
        u_out[2] = uz / nrm;
    }
}

// ---------------------------------------------------------------------------
// Merged mid kernel: block 0 = exclusive prefix scan; block 1 = global MLP
// (first reducing the gsum replicas).
// ---------------------------------------------------------------------------
__global__ __launch_bounds__(1024) void mid_kernel(
    const int* __restrict__ deg_int, int* __restrict__ rowstart,
    int* __restrict__ cursor,
    const float* __restrict__ gsum,
    const float* __restrict__ glw1, const float* __restrict__ glb1,
    const float* __restrict__ glw2, const float* __restrict__ glb2,
    const float* __restrict__ glw3, const float* __restrict__ glb3,
    const float* __restrict__ res_scale,
    unsigned short* __restrict__ gctxb, float* __restrict__ tres) {
    int t = threadIdx.x;
    if (blockIdx.x == 0) {
        __shared__ int wsum[16];
        __shared__ int run;
        int wid = t >> 6, lane = t & 63;
        int4 vs[13];
#pragma unroll
        for (int chunk = 0; chunk < 13; chunk++) {
            int base = chunk * 4096 + t * 4;
            int4 v = {0, 0, 0, 0};
            if (base + 3 < N_NODES) {
                v = *(const int4*)(deg_int + base);
            } else {
                if (base < N_NODES) v.x = deg_int[base];
                if (base + 1 < N_NODES) v.y = deg_int[base + 1];
                if (base + 2 < N_NODES) v.z = deg_int[base + 2];
                if (base + 3 < N_NODES) v.w = deg_int[base + 3];
            }
            vs[chunk] = v;
        }
        if (t == 0) run = 0;
        __syncthreads();
#pragma unroll
        for (int chunk = 0; chunk < 13; chunk++) {
            int base = chunk * 4096 + t * 4;
            int4 v = vs[chunk];
            int s1 = v.x, s2 = s1 + v.y, s3 = s2 + v.z, s4 = s3 + v.w;
            int x = s4;
#pragma unroll
            for (int off = 1; off < 64; off <<= 1) {
                int y = __shfl_up(x, off, 64);
                if (lane >= off) x += y;
            }
            if (lane == 63) wsum[wid] = x;
            __syncthreads();
            if (t < 16) {
                int sv = wsum[t];
#pragma unroll
                for (int off = 1; off < 16; off <<= 1) {
                    int y = __shfl_up(sv, off, 16);
                    if (t >= off) sv += y;
                }
                wsum[t] = sv;
            }
            __syncthreads();
            int run_l = run;
            int wpre = (wid == 0) ? 0 : wsum[wid - 1];
            int toff = run_l + wpre + (x - s4);
            int e0 = toff, e1 = toff + s1, e2 = toff + s2, e3 = toff + s3;
            if (base <= N_NODES) rowstart[base] = e0;
            if (base + 1 <= N_NODES) rowstart[base + 1] = e1;
            if (base + 2 <= N_NODES) rowstart[base + 2] = e2;
            if (base + 3 <= N_NODES) rowstart[base + 3] = e3;
            if (base < N_NODES) cursor[base] = e0;
            if (base + 1 < N_NODES) cursor[base + 1] = e1;
            if (base + 2 < N_NODES) cursor[base + 2] = e2;
            if (base + 3 < N_NODES) cursor[base + 3] = e3;
            __syncthreads();
            if (t == 0) run = run_l + wsum[15];
            __syncthreads();
        }
    } else {
        __shared__ float a[64], b[64];
        float s = 0.0f;
        if (t < 64) {
            float acc = 0.0f;
            for (int r = 0; r < GSUM_REP; r++) acc += gsum[r * 64 + t];
            a[t] = acc * (1.0f / (float)N_NODES);
        }
        __syncthreads();
        if (t < 64) {
            s = glb1[t];
            for (int k = 0; k < 64; k++) s += a[k] * glw1[k * 64 + t];
            b[t] = gelu_fast(s);
        }
        __syncthreads();
        if (t < 64) {
            s = glb2[t];
            for (int k = 0; k < 64; k++) s += b[k] * glw2[k * 64 + t];
        }
        __syncthreads();
        if (t < 64) a[t] = gelu_fast(s);
        __syncthreads();
        if (t < 64) {
            s = glb3[t];
            for (int k = 0; k < 64; k++) s += a[k] * glw3[k * 64 + t];
            gctxb[t] = f2bf(s);
        }
        if (t == 0) *tres = tanhf(res_scale[0]);
    }
}

// ---------------------------------------------------------------------------
// Fused MFMA edge pipeline: 64 edges/block, 4 waves x 16 rows.
// Single wave-private LDS slice hosts edge_input -> H1 -> H2 -> H3 in
// sequence (in-wave RAW order is compiler-enforced). No fp32 h3 register
// copy: the gate reads bf16 H3 from LDS and the msg writer re-reads +
// gate-scales it in row layout. Peak live regs ~ acc[8] only ->
// launch_bounds(256,6) cannot spill (cap 85 VGPR). LDS 22.3 KB.
// ---------------------------------------------------------------------------
struct SmemE {
    unsigned short x1[64 * XS1];   // 21504 B, all pipeline stages live here
    float gate[64];
    int pos[64];
    int rows[64];
};

__global__ __launch_bounds__(256, 6) void edge_kernel(
    const float* __restrict__ coords, const int* __restrict__ eidx,
    const unsigned short* __restrict__ featb, const float* __restrict__ u,
    const unsigned short* __restrict__ frags,
    const float* __restrict__ eb1, const float* __restrict__ eb2,
    const float* __restrict__ eb3,
    const float* __restrict__ gb1, const float* __restrict__ gw2,
    const float* __restrict__ gb2,
    int* __restrict__ cursor, unsigned short* __restrict__ msg,
    float* __restrict__ agg, int use_msg) {
    __shared__ SmemE sm;
    int t = threadIdx.x;
    int wv = t >> 6;
    int lane = t & 63;
    int e0 = blockIdx.x * 64;
    unsigned short* slice = sm.x1 + wv * 16 * XS1;   // wave-private

    {   // stage folded edge_input (bf16 copies, no cvt): 4 threads/edge
        int le = t >> 2, sub = t & 3;
        int e = e0 + le;
        int row = eidx[e];
        int col = eidx[N_EDGES + e];
        const uint4* fi4 = (const uint4*)(featb + (long)row * CDIM);
        const uint4* fj4 = (const uint4*)(featb + (long)col * CDIM);
        unsigned short* xr = sm.x1 + le * XS1;
        *(uint4*)(xr + sub * 16) = fi4[sub * 2];
        *(uint4*)(xr + sub * 16 + 8) = fi4[sub * 2 + 1];
        *(uint4*)(xr + 64 + sub * 16) = fj4[sub * 2];
        *(uint4*)(xr + 64 + sub * 16 + 8) = fj4[sub * 2 + 1];
        ushort4 z = {0, 0, 0, 0};
        if (sub == 0) {
            sm.rows[le] = row;
            sm.pos[le] = atomicAdd(&cursor[row], 1);  // cursor pre-seeded = rowstart
            float xix = coords[row * 3], xiy = coords[row * 3 + 1], xiz = coords[row * 3 + 2];
            float xjx = coords[col * 3], xjy = coords[col * 3 + 1], xjz = coords[col * 3 + 2];
            float rx = xix - xjx, ry = xiy - xjy, rz = xiz - xjz;
            float ux = u[0], uy = u[1], uz = u[2];
            float4 sc;
            sc.x = rx * rx + ry * ry + rz * rz;
            sc.y = xix * ux + xiy * uy + xiz * uz;
            sc.z = xjx * ux + xjy * uy + xjz * uz;
            sc.w = rx * ux + ry * uy + rz * uz;
            *(ushort4*)(xr + 128) = pack4(sc);
        } else if (sub == 1) {
            *(ushort4*)(xr + 132) = z; *(ushort4*)(xr + 136) = z; *(ushort4*)(xr + 140) = z;
        } else if (sub == 2) {
            *(ushort4*)(xr + 144) = z; *(ushort4*)(xr + 148) = z;
        } else {
            *(ushort4*)(xr + 152) = z; *(ushort4*)(xr + 156) = z;
        }
    }
    __syncthreads();

    floatx4 acc[8];

    // L1 (folded, K=160): reads slice @XS1, writes H1 into slice @HS
    bias_init<8>(acc, eb1, lane);
    mfma_layer<5, 8>(slice, XS1, frags + F1_OFF, lane, acc);
    epilogue_store<true, 8>(acc, slice, HS, lane);
    __syncthreads();

    // L2: H1 -> H2 (same slice; in-wave sequential)
    bias_init<8>(acc, eb2, lane);
    mfma_layer<4, 8>(slice, HS, frags + F2_OFF, lane, acc);
    epilogue_store<true, 8>(acc, slice, HS, lane);
    __syncthreads();

    // L3: H2 -> H3 (bf16, stays in LDS; no fp32 register copy)
    bias_init<8>(acc, eb3, lane);
    mfma_layer<4, 8>(slice, HS, frags + F3_OFF, lane, acc);
    epilogue_store<false, 8>(acc, slice, HS, lane);
    __syncthreads();

    // Gate (reads bf16 H3 from slice)
    bias_init<8>(acc, gb1, lane);
    mfma_layer<4, 8>(slice, HS, frags + FG_OFF, lane, acc);
    {
        int q = lane >> 4, c = lane & 15;
        f32x2 p01 = {0.0f, 0.0f}, p23 = {0.0f, 0.0f};
#pragma unroll
        for (int ct = 0; ct < 8; ct++) {
            float w2 = gw2[ct * 16 + c];
            f32x2 g01 = gelu_pk((f32x2){acc[ct][0], acc[ct][1]});
            f32x2 g23 = gelu_pk((f32x2){acc[ct][2], acc[ct][3]});
            p01 += g01 * w2;
            p23 += g23 * w2;
        }
        float p[4] = {p01.x, p01.y, p23.x, p23.y};
#pragma unroll
        for (int i = 0; i < 4; i++) {
#pragma unroll
            for (int mask = 1; mask < 16; mask <<= 1) p[i] += __shfl_xor(p[i], mask, 64);
        }
        if (c == 0) {
            float gb = gb2[0];
#pragma unroll
            for (int i = 0; i < 4; i++) {
                float z = p[i] + gb;
                sm.gate[wv * 16 + q * 4 + i] = 1.0f / (1.0f + __expf(-z));
            }
        }
    }
    __syncthreads();

    // Stream gate-scaled H3 rows (read back from LDS in row layout)
    {
        int le = t >> 2, sub = t & 3;
        float g = sm.gate[le];
        const unsigned short* src = sm.x1 + (le >> 4) * 16 * XS1 + (le & 15) * HS;
        if (use_msg) {
            long basep = (long)sm.pos[le] * MCDIM;
#pragma unroll
            for (int m = 0; m < 4; m++) {
                int off = m * 32 + sub * 8;
                uint4 v = *(const uint4*)(src + off);
                uint4 o;
                o.x = bfscale2(v.x, g);
                o.y = bfscale2(v.y, g);
                o.z = bfscale2(v.z, g);
                o.w = bfscale2(v.w, g);
                *(uint4*)(msg + basep + off) = o;
            }
        } else {
            int row = sm.rows[le];
            float* agr = agg + (long)row * MCDIM;
#pragma unroll
            for (int m = 0; m < 4; m++) {
                int off = m * 32 + sub * 8;
                uint4 v = *(const uint4*)(src + off);
                atomicAdd(agr + off + 0, bf2f(v.x & 0xffffu) * g);
                atomicAdd(agr + off + 1, bf2f(v.x >> 16) * g);
                atomicAdd(agr + off + 2, bf2f(v.y & 0xffffu) * g);
                atomicAdd(agr + off + 3, bf2f(v.y >> 16) * g);
                atomicAdd(agr + off + 4, bf2f(v.z & 0xffffu) * g);
                atomicAdd(agr + off + 5, bf2f(v.z >> 16) * g);
                atomicAdd(agr + off + 6, bf2f(v.w & 0xffffu) * g);
                atomicAdd(agr + off + 7, bf2f(v.w >> 16) * g);
            }
        }
    }
}

// ---------------------------------------------------------------------------
// Gather: one wave per node; lane loads uint2 spanning TWO msg rows/iter.
// ---------------------------------------------------------------------------
__global__ __launch_bounds__(256) void gather_kernel(
    const int* __restrict__ rowstart, const unsigned short* __restrict__ msg,
    const float* __restrict__ agg, int use_msg,
    unsigned short* __restrict__ aggb) {
    int wv = threadIdx.x >> 6, lane = threadIdx.x & 63;
    int n = blockIdx.x * 4 + wv;
    if (n >= N_NODES) return;
    int rs = rowstart[n], re = rowstart[n + 1];
    int deg = re - rs;
    float a0 = 0.0f, a1 = 0.0f, a2 = 0.0f, a3 = 0.0f;
    if (use_msg) {
        const unsigned short* base = msg + (long)rs * MCDIM;
        int pairs = deg >> 1;
        for (int i = 0; i < pairs; i++) {
            uint2 v = *(const uint2*)(base + i * 256 + lane * 4);
            a0 += bf2f(v.x & 0xffffu); a1 += bf2f(v.x >> 16);
            a2 += bf2f(v.y & 0xffffu); a3 += bf2f(v.y >> 16);
        }
        if ((deg & 1) && lane < 32) {
            uint2 v = *(const uint2*)(base + (deg - 1) * MCDIM + lane * 4);
            a0 += bf2f(v.x & 0xffffu); a1 += bf2f(v.x >> 16);
            a2 += bf2f(v.y & 0xffffu); a3 += bf2f(v.y >> 16);
        }
        a0 += __shfl_xor(a0, 32, 64);
        a1 += __shfl_xor(a1, 32, 64);
        a2 += __shfl_xor(a2, 32, 64);
        a3 += __shfl_xor(a3, 32, 64);
    } else if (lane < 32) {
        const float4 v = *(const float4*)(agg + (long)n * MCDIM + lane * 4);
        a0 = v.x; a1 = v.y; a2 = v.z; a3 = v.w;
    }
    if (lane < 32) {
        float inv = 1.0f / fmaxf((float)deg, 1.0f);
        uint2 o;
        o.x = f2bf2(a0 * inv, a1 * inv);
        o.y = f2bf2(a2 * inv, a3 * inv);
        *(uint2*)(aggb + (long)n * MCDIM + lane * 4) = o;
    }
}

// ---------------------------------------------------------------------------
// MFMA node update: single-buffer slices. 64 nodes/block, 4 blocks/CU.
// ---------------------------------------------------------------------------
struct SmemU {
    unsigned short ui[64 * UST];   // 33792 B, all stages live here
};

__global__ __launch_bounds__(256, 4) void update_kernel(
    const unsigned short* __restrict__ featb, const unsigned short* __restrict__ aggb,
    const unsigned short* __restrict__ gctxb, const float* __restrict__ tres,
    const unsigned short* __restrict__ frags,
    const float* __restrict__ ub1, const float* __restrict__ ub2,
    const float* __restrict__ ub3,
    float* __restrict__ out) {
    __shared__ SmemU sm;
    int t = threadIdx.x;
    int wv = t >> 6;
    int lane = t & 63;
    int n0 = blockIdx.x * 64;
    unsigned short* slice = sm.ui + wv * 16 * UST;   // wave-private

    {   // stage [feat | agg | gctx] (all bf16 copies): 4 threads/node
        int ln = t >> 2, sub = t & 3;
        int n = n0 + ln;
        unsigned short* ur = sm.ui + ln * UST;
        if (n < N_NODES) {
            const uint4* f4 = (const uint4*)(featb + (long)n * CDIM);
            *(uint4*)(ur + sub * 16) = f4[sub * 2];
            *(uint4*)(ur + sub * 16 + 8) = f4[sub * 2 + 1];
            const uint4* a4 = (const uint4*)(aggb + (long)n * MCDIM);
            *(uint4*)(ur + 64 + sub * 32) = a4[sub * 4];
            *(uint4*)(ur + 64 + sub * 32 + 8) = a4[sub * 4 + 1];
            *(uint4*)(ur + 64 + sub * 32 + 16) = a4[sub * 4 + 2];
            *(uint4*)(ur + 64 + sub * 32 + 24) = a4[sub * 4 + 3];
            const uint4* g4 = (const uint4*)gctxb;
            *(uint4*)(ur + 192 + sub * 16) = g4[sub * 2];
            *(uint4*)(ur + 192 + sub * 16 + 8) = g4[sub * 2 + 1];
        } else {
            uint4 z = {0, 0, 0, 0};
#pragma unroll
            for (int m = 0; m < 8; m++) *(uint4*)(ur + sub * 64 + m * 8) = z;
        }
    }
    __syncthreads();

    floatx4 acc[8];
    bias_init<8>(acc, ub1, lane);
    mfma_layer<8, 8>(slice, UST, frags + FU1_OFF, lane, acc);
    epilogue_store<true, 8>(acc, slice, HS, lane);
    __syncthreads();

    bias_init<8>(acc, ub2, lane);
    mfma_layer<4, 8>(slice, HS, frags + FU2_OFF, lane, acc);
    epilogue_store<true, 8>(acc, slice, HS, lane);
    __syncthreads();

    floatx4 acc3[4];
    bias_init<4>(acc3, ub3, lane);
    mfma_layer<4, 4>(slice, HS, frags + FU3_OFF, lane, acc3);
    {
        int q = lane >> 4, c = lane & 15;
        float tr = *tres;
#pragma unroll
        for (int ct = 0; ct < 4; ct++) {
#pragma unroll
            for (int i = 0; i < 4; i++) {
                int n = n0 + wv * 16 + q * 4 + i;
                if (n < N_NODES) out[(long)n * CDIM + ct * 16 + c] = acc3[ct][i] * tr;
            }
        }
    }
}

// ---------------------------------------------------------------------------
extern "C" void kernel_launch(void* const* d_in, const int* in_sizes, int n_in,
                              void* d_out, int out_size, void* d_ws, size_t ws_size,
                              hipStream_t stream) {
    const float* coords = (const float*)d_in[0];
    const float* h = (const float*)d_in[1];
    const float* flow = (const float*)d_in[2];
    const int* eidx = (const int*)d_in[3];
    const float* ln_g = (const float*)d_in[4];
    const float* ln_b = (const float*)d_in[5];
    const float* ew1 = (const float*)d_in[6];
    const float* eb1 = (const float*)d_in[7];
    const float* ew2 = (const float*)d_in[8];
    const float* eb2 = (const float*)d_in[9];
    const float* ew3 = (const float*)d_in[10];
    const float* eb3 = (const float*)d_in[11];
    const float* gw1 = (const float*)d_in[12];
    const float* gb1 = (const float*)d_in[13];
    const float* gw2 = (const float*)d_in[14];
    const float* gb2 = (const float*)d_in[15];
    const float* glw1 = (const float*)d_in[16];
    const float* glb1 = (const float*)d_in[17];
    const float* glw2 = (const float*)d_in[18];
    const float* glb2 = (const float*)d_in[19];
    const float* glw3 = (const float*)d_in[20];
    const float* glb3 = (const float*)d_in[21];
    const float* uw1 = (const float*)d_in[22];
    const float* ub1 = (const float*)d_in[23];
    const float* uw2 = (const float*)d_in[24];
    const float* ub2 = (const float*)d_in[25];
    const float* uw3 = (const float*)d_in[26];
    const float* ub3 = (const float*)d_in[27];
    const float* res = (const float*)d_in[28];

    // ---- workspace carve-up ----
    char* base = (char*)d_ws;
    unsigned short* frags = (unsigned short*)base;                 // FRAG_TOTAL us
    unsigned short* featb = (unsigned short*)(base + FRAG_TOTAL * 2); // N*64 us
    unsigned short* aggb = featb + (size_t)N_NODES * CDIM;         // N*128 us
    unsigned short* gctxb = aggb + (size_t)N_NODES * MCDIM;        // 64 us
    float* gsum = (float*)(gctxb + 64);                            // 32*64
    float* u = gsum + GSUM_REP * 64;                               // 4
    float* tres = u + 4;                                           // 1
    int* rowstart = (int*)(tres + 1);                              // N+1
    int* cursor = rowstart + (N_NODES + 1);                        // N
    int* deg_int = cursor + N_NODES;                               // N
    char* tail = (char*)(deg_int + N_NODES);
    tail = (char*)(((uintptr_t)tail + 255) & ~(uintptr_t)255);
    size_t head_bytes = (size_t)(tail - base);
    size_t msg_bytes = (size_t)N_EDGES * MCDIM * 2;                // 204.8 MB bf16
    int use_msg = (ws_size >= head_bytes + msg_bytes) ? 1 : 0;
    unsigned short* msg = (unsigned short*)tail;                   // CSR slots
    float* agg = (float*)tail;                                     // fallback

    if (!use_msg)
        hipMemsetAsync(agg, 0, (size_t)N_NODES * MCDIM * sizeof(float), stream);

    prep_frags<<<FRAG_TOTAL / 256, 256, 0, stream>>>(ew1, ew2, ew3, gw1,
                                                     uw1, uw2, uw3, frags,
                                                     deg_int, gsum);
    ln_count_kernel<<<N_NODES / 4, 256, 0, stream>>>(h, ln_g, ln_b, flow, eidx,
                                                     featb, gsum, u, deg_int);
    mid_kernel<<<2, 1024, 0, stream>>>(deg_int, rowstart, cursor, gsum,
                                       glw1, glb1, glw2, glb2, glw3, glb3,
                                       res, gctxb, tres);
    edge_kernel<<<N_EDGES / 64, 256, 0, stream>>>(coords, eidx, featb, u, frags,
                                                  eb1, eb2, eb3, gb1, gw2, gb2,
                                                  cursor, msg, agg, use_msg);
    gather_kernel<<<(N_NODES + 3) / 4, 256, 0, stream>>>(rowstart, msg, agg,
                                                         use_msg, aggb);
    update_kernel<<<(N_NODES + 63) / 64, 256, 0, stream>>>(featb, aggb, gctxb,
                                                           tres, frags,
                                                           ub1, ub2, ub3,
                                                           (float*)d_out);
}

// Round 11
// 529.869 us; speedup vs baseline: 1.2220x; 1.1493x over previous
//
#include <hip/hip_runtime.h>
#include <hip/hip_bf16.h>
#include <math.h>

#define N_NODES 50000
#define N_EDGES 800000
#define CDIM 64
#define MCDIM 128
#define GSUM_REP 32   // gsum replication factor (atomic decontention)

// bf16 LDS strides (elements). Row stride in dwords must be == 4 (mod 8) so
// the 16-row A-fragment ds_read_b128 pattern lands 2 lanes/bank (free, m136).
#define XS1 168       // folded edge_input, K = 132 padded -> 160 (84 dw % 8 == 4)
#define HS  136       // hidden layers, K=128                (68 dw % 8 == 4)
#define UST 264       // update_input, K=256                (132 dw % 8 == 4)

typedef __attribute__((ext_vector_type(8))) short short8;
typedef __attribute__((ext_vector_type(4))) float floatx4;
typedef __attribute__((ext_vector_type(2))) float f32x2;

// A&S 7.1.27 erf (abs err 5e-4) gelu, scalar form (used in small kernels).
__device__ __forceinline__ float gelu_fast(float x) {
    float z = fabsf(x) * 0.70710678f;
    float w = fmaf(z, fmaf(z, fmaf(z, fmaf(z, 0.078108f, 0.000972f),
                                   0.230389f), 0.278393f), 1.0f);
    float w2 = w * w;
    float r = __builtin_amdgcn_rcpf(w2 * w2);
    float m = 0.5f * fabsf(x);
    return fmaf(-m, r, fmaf(0.5f, x, m));
}

// Packed-pair gelu: identical per-element math; float2 vector arithmetic lets
// LLVM emit dual-issue v_pk_{mul,add,fma}_f32. rcp stays scalar.
__device__ __forceinline__ f32x2 gelu_pk(f32x2 x) {
    f32x2 ax = __builtin_elementwise_abs(x);
    f32x2 z = ax * 0.70710678f;
    f32x2 w = z * (z * (z * (z * 0.078108f + 0.000972f) + 0.230389f)
                   + 0.278393f) + 1.0f;
    f32x2 w2 = w * w;
    f32x2 w4 = w2 * w2;
    f32x2 r;
    r.x = __builtin_amdgcn_rcpf(w4.x);
    r.y = __builtin_amdgcn_rcpf(w4.y);
    f32x2 m = 0.5f * ax;
    return 0.5f * x + m - m * r;
}

__device__ __forceinline__ unsigned short f2bf(float f) {  // RNE fp32->bf16
    unsigned int u = __float_as_uint(f);
    unsigned int r = u + 0x7fffu + ((u >> 16) & 1u);
    return (unsigned short)(r >> 16);
}
__device__ __forceinline__ float bf2f(unsigned int lo16) {
    return __uint_as_float(lo16 << 16);
}
// packed 2x fp32 -> bf16 pair (v_cvt_pk_bf16_f32 on gfx950)
__device__ __forceinline__ unsigned int f2bf2(float lo, float hi) {
    __hip_bfloat162 v = __float22bfloat162_rn(make_float2(lo, hi));
    union { __hip_bfloat162 b; unsigned int u; } cv;
    cv.b = v;
    return cv.u;
}
__device__ __forceinline__ ushort4 pack4(float4 v) {
    ushort4 r;
    r.x = f2bf(v.x); r.y = f2bf(v.y); r.z = f2bf(v.z); r.w = f2bf(v.w);
    return r;
}

// ---------------------------------------------------------------------------
// Weight fragment pre-swizzle. B-fragment for 16x16x32: lane l holds
// B[k = k0 + (l>>4)*8 + j][n = 16*ct + (l&15)], j=0..7 -> contiguous 16B/lane.
// ew1 is FOLDED: k<64 -> Wi+Wd ; 64..127 -> Wj-Wd ; 128..131 -> geo ; pad 160.
// Also zero-inits deg_int/gsum replicas.
// ---------------------------------------------------------------------------
#define F1_OFF 0               // folded ew1: 5 chunks (K=160), N=128
#define F2_OFF (5 * 4096)      // ew2: 4
#define F3_OFF (9 * 4096)      // ew3: 4
#define FG_OFF (13 * 4096)     // gw1: 4
#define FU1_OFF (17 * 4096)    // uw1: 8 (K=256)
#define FU2_OFF (25 * 4096)    // uw2: 4
#define FU3_OFF (29 * 4096)    // uw3: 4 chunks x 2048 (N=64)
#define FRAG_TOTAL (29 * 4096 + 4 * 2048)   // 126976 ushorts

__global__ __launch_bounds__(256) void prep_frags(
    const float* __restrict__ ew1, const float* __restrict__ ew2,
    const float* __restrict__ ew3, const float* __restrict__ gw1,
    const float* __restrict__ uw1, const float* __restrict__ uw2,
    const float* __restrict__ uw3, unsigned short* __restrict__ frags,
    int* __restrict__ deg_int, float* __restrict__ gsum) {
    int idx = blockIdx.x * 256 + threadIdx.x;
    if (idx < N_NODES) deg_int[idx] = 0;
    if (idx < GSUM_REP * 64) gsum[idx] = 0.0f;
    if (idx >= FRAG_TOTAL) return;
    if (idx < F2_OFF) {  // folded ew1
        int chunk = idx >> 12;
        int rem = idx & 4095;
        int ct = rem >> 9;
        int lane = (rem >> 3) & 63;
        int j = rem & 7;
        int k = chunk * 32 + (lane >> 4) * 8 + j;
        int n = ct * 16 + (lane & 15);
        float v;
        if (k < 64)       v = ew1[k * 128 + n] + ew1[(128 + k) * 128 + n];
        else if (k < 128) v = ew1[k * 128 + n] - ew1[(64 + k) * 128 + n];
        else if (k < 132) v = ew1[(192 + k - 128) * 128 + n];
        else              v = 0.0f;
        frags[idx] = f2bf(v);
    } else if (idx < FU3_OFF) {
        int chunk = idx >> 12;
        int rem = idx & 4095;
        int ct = rem >> 9;
        int lane = (rem >> 3) & 63;
        int j = rem & 7;
        const float* W; int kbase;
        if (chunk < 9)       { W = ew2; kbase = (chunk - 5) * 32; }
        else if (chunk < 13) { W = ew3; kbase = (chunk - 9) * 32; }
        else if (chunk < 17) { W = gw1; kbase = (chunk - 13) * 32; }
        else if (chunk < 25) { W = uw1; kbase = (chunk - 17) * 32; }
        else                 { W = uw2; kbase = (chunk - 25) * 32; }
        int k = kbase + (lane >> 4) * 8 + j;
        int n = ct * 16 + (lane & 15);
        frags[idx] = f2bf(W[k * 128 + n]);
    } else {  // uw3 [128][64]
        int rem = idx - FU3_OFF;
        int chunk = rem >> 11;
        int r = rem & 2047;
        int ct = r >> 9;
        int lane = (r >> 3) & 63;
        int j = r & 7;
        int k = chunk * 32 + (lane >> 4) * 8 + j;
        int n = ct * 16 + (lane & 15);
        frags[idx] = f2bf(uw3[k * 64 + n]);
    }
}

// ---------------------------------------------------------------------------
// MFMA helpers. acc init = column-broadcast bias.
// ---------------------------------------------------------------------------
template <int NCT>
__device__ __forceinline__ void bias_init(floatx4* acc,
                                          const float* __restrict__ bias, int lane) {
    int c = lane & 15;
#pragma unroll
    for (int ct = 0; ct < NCT; ct++) {
        float b = bias[ct * 16 + c];
        acc[ct][0] = b; acc[ct][1] = b; acc[ct][2] = b; acc[ct][3] = b;
    }
}

template <int NCH, int NCT>
__device__ __forceinline__ void mfma_layer(const unsigned short* Xl, int xs,
                                           const unsigned short* __restrict__ F,
                                           int lane, floatx4* acc) {
    int q = lane >> 4, c = lane & 15;
    const unsigned short* xrow = Xl + c * xs + q * 8;
    for (int k0 = 0; k0 < NCH; k0++) {
        short8 a = *(const short8*)(xrow + k0 * 32);
#pragma unroll
        for (int ct = 0; ct < NCT; ct++) {
            short8 b = *(const short8*)(F + ((k0 * NCT + ct) * 64 + lane) * 8);
            acc[ct] = __builtin_amdgcn_mfma_f32_16x16x32_bf16(a, b, acc[ct], 0, 0, 0);
        }
    }
}

// (opt) packed gelu + packed-bf16 store into an A-layout LDS tile.
// C layout: value (ct,i) at row (lane>>4)*4+i, col 16*ct+(lane&15).
template <bool GELU, int NCT>
__device__ __forceinline__ void epilogue_store(floatx4* acc,
                                               unsigned short* dst, int xs, int lane) {
    int q = lane >> 4, c = lane & 15;
    unsigned short* base = dst + (q * 4) * xs + c;
#pragma unroll
    for (int ct = 0; ct < NCT; ct++) {
        f32x2 v01 = {acc[ct][0], acc[ct][1]};
        f32x2 v23 = {acc[ct][2], acc[ct][3]};
        if (GELU) { v01 = gelu_pk(v01); v23 = gelu_pk(v23); }
        unsigned int p01 = f2bf2(v01.x, v01.y), p23 = f2bf2(v23.x, v23.y);
        unsigned short* p = base + ct * 16;
        p[0]      = (unsigned short)p01;
        p[xs]     = (unsigned short)(p01 >> 16);
        p[2 * xs] = (unsigned short)p23;
        p[3 * xs] = (unsigned short)(p23 >> 16);
    }
}

// ---------------------------------------------------------------------------
// LayerNorm (bf16 out) + global-mean partials (replicated atomics)
// + flow_dir normalize + degree
// ---------------------------------------------------------------------------
__global__ __launch_bounds__(256) void ln_count_kernel(
    const float* __restrict__ h, const float* __restrict__ ln_g,
    const float* __restrict__ ln_b, const float* __restrict__ flow_dir,
    const int* __restrict__ eidx, unsigned short* __restrict__ featb,
    float* __restrict__ gsum, float* __restrict__ u_out,
    int* __restrict__ deg_int) {
    int t = threadIdx.x;
    int ln = t >> 6;
    int c = t & 63;
    int n = blockIdx.x * 4 + ln;

    float x = h[n * CDIM + c];
    float s = x;
#pragma unroll
    for (int off = 32; off > 0; off >>= 1) s += __shfl_xor(s, off, 64);
    float mu = s * (1.0f / 64.0f);
    float d = x - mu;
    float v = d * d;
#pragma unroll
    for (int off = 32; off > 0; off >>= 1) v += __shfl_xor(v, off, 64);
    float rs = 1.0f / sqrtf(v * (1.0f / 64.0f) + 1e-5f);
    float f = d * rs * ln_g[c] + ln_b[c];
    featb[n * CDIM + c] = f2bf(f);

    __shared__ float fs[4][64];
    fs[ln][c] = f;
    __syncthreads();   // cross-wave reduction below
    if (t < 64) {
        float p = fs[0][t] + fs[1][t] + fs[2][t] + fs[3][t];
        atomicAdd(&gsum[(blockIdx.x & (GSUM_REP - 1)) * 64 + t], p);
        int e = blockIdx.x * 64 + t;           // 12500*64 == N_EDGES
        atomicAdd(&deg_int[eidx[e]], 1);
    }
    if (blockIdx.x == 0 && t == 0) {
        float ux = flow_dir[0], uy = flow_dir[1], uz = flow_dir[2];
        float nrm = sqrtf(ux * ux + uy * uy + uz * uz) + 1e-8f;
        u_out[0] = ux / nrm;
        u_out[1] = uy / nrm;
        u_out[2] = uz / nrm;
    }
}

// ---------------------------------------------------------------------------
// Merged mid kernel: block 0 = exclusive prefix scan; block 1 = global MLP
// (first reducing the gsum replicas).
// ---------------------------------------------------------------------------
__global__ __launch_bounds__(1024) void mid_kernel(
    const int* __restrict__ deg_int, int* __restrict__ rowstart,
    int* __restrict__ cursor,
    const float* __restrict__ gsum,
    const float* __restrict__ glw1, const float* __restrict__ glb1,
    const float* __restrict__ glw2, const float* __restrict__ glb2,
    const float* __restrict__ glw3, const float* __restrict__ glb3,
    const float* __restrict__ res_scale,
    unsigned short* __restrict__ gctxb, float* __restrict__ tres) {
    int t = threadIdx.x;
    if (blockIdx.x == 0) {
        __shared__ int wsum[16];
        __shared__ int run;
        int wid = t >> 6, lane = t & 63;
        int4 vs[13];
#pragma unroll
        for (int chunk = 0; chunk < 13; chunk++) {
            int base = chunk * 4096 + t * 4;
            int4 v = {0, 0, 0, 0};
            if (base + 3 < N_NODES) {
                v = *(const int4*)(deg_int + base);
            } else {
                if (base < N_NODES) v.x = deg_int[base];
                if (base + 1 < N_NODES) v.y = deg_int[base + 1];
                if (base + 2 < N_NODES) v.z = deg_int[base + 2];
                if (base + 3 < N_NODES) v.w = deg_int[base + 3];
            }
            vs[chunk] = v;
        }
        if (t == 0) run = 0;
        __syncthreads();
#pragma unroll
        for (int chunk = 0; chunk < 13; chunk++) {
            int base = chunk * 4096 + t * 4;
            int4 v = vs[chunk];
            int s1 = v.x, s2 = s1 + v.y, s3 = s2 + v.z, s4 = s3 + v.w;
            int x = s4;
#pragma unroll
            for (int off = 1; off < 64; off <<= 1) {
                int y = __shfl_up(x, off, 64);
                if (lane >= off) x += y;
            }
            if (lane == 63) wsum[wid] = x;
            __syncthreads();
            if (t < 16) {
                int sv = wsum[t];
#pragma unroll
                for (int off = 1; off < 16; off <<= 1) {
                    int y = __shfl_up(sv, off, 16);
                    if (t >= off) sv += y;
                }
                wsum[t] = sv;
            }
            __syncthreads();
            int run_l = run;
            int wpre = (wid == 0) ? 0 : wsum[wid - 1];
            int toff = run_l + wpre + (x - s4);
            int e0 = toff, e1 = toff + s1, e2 = toff + s2, e3 = toff + s3;
            if (base <= N_NODES) rowstart[base] = e0;
            if (base + 1 <= N_NODES) rowstart[base + 1] = e1;
            if (base + 2 <= N_NODES) rowstart[base + 2] = e2;
            if (base + 3 <= N_NODES) rowstart[base + 3] = e3;
            if (base < N_NODES) cursor[base] = e0;
            if (base + 1 < N_NODES) cursor[base + 1] = e1;
            if (base + 2 < N_NODES) cursor[base + 2] = e2;
            if (base + 3 < N_NODES) cursor[base + 3] = e3;
            __syncthreads();
            if (t == 0) run = run_l + wsum[15];
            __syncthreads();
        }
    } else {
        __shared__ float a[64], b[64];
        float s = 0.0f;
        if (t < 64) {
            float acc = 0.0f;
            for (int r = 0; r < GSUM_REP; r++) acc += gsum[r * 64 + t];
            a[t] = acc * (1.0f / (float)N_NODES);
        }
        __syncthreads();
        if (t < 64) {
            s = glb1[t];
            for (int k = 0; k < 64; k++) s += a[k] * glw1[k * 64 + t];
            b[t] = gelu_fast(s);
        }
        __syncthreads();
        if (t < 64) {
            s = glb2[t];
            for (int k = 0; k < 64; k++) s += b[k] * glw2[k * 64 + t];
        }
        __syncthreads();
        if (t < 64) a[t] = gelu_fast(s);
        __syncthreads();
        if (t < 64) {
            s = glb3[t];
            for (int k = 0; k < 64; k++) s += a[k] * glw3[k * 64 + t];
            gctxb[t] = f2bf(s);
        }
        if (t == 0) *tres = tanhf(res_scale[0]);
    }
}

// ---------------------------------------------------------------------------
// Fused MFMA edge pipeline: 64 edges/block, 4 waves x 16 rows.
// R8 compute structure (h3 in fp32 regs, C-layout scaled store, no msg LDS
// re-read) + single wave-private LDS slice (22.3 KB).
// launch_bounds(256,5): VGPR cap 102 >> ~90 live set -> no spills, and
// enough regs to pipeline B-fragment loads. 5-6 blocks/CU (vs R8's 4).
// ---------------------------------------------------------------------------
struct SmemE {
    unsigned short x1[64 * XS1];   // 21504 B, all pipeline stages live here
    float gate[64];
    int pos[64];
    int rows[64];
};

__global__ __launch_bounds__(256, 5) void edge_kernel(
    const float* __restrict__ coords, const int* __restrict__ eidx,
    const unsigned short* __restrict__ featb, const float* __restrict__ u,
    const unsigned short* __restrict__ frags,
    const float* __restrict__ eb1, const float* __restrict__ eb2,
    const float* __restrict__ eb3,
    const float* __restrict__ gb1, const float* __restrict__ gw2,
    const float* __restrict__ gb2,
    int* __restrict__ cursor, unsigned short* __restrict__ msg,
    float* __restrict__ agg, int use_msg) {
    __shared__ SmemE sm;
    int t = threadIdx.x;
    int wv = t >> 6;
    int lane = t & 63;
    int e0 = blockIdx.x * 64;
    unsigned short* slice = sm.x1 + wv * 16 * XS1;   // wave-private

    {   // stage folded edge_input (bf16 copies, no cvt): 4 threads/edge
        int le = t >> 2, sub = t & 3;
        int e = e0 + le;
        int row = eidx[e];
        int col = eidx[N_EDGES + e];
        const uint4* fi4 = (const uint4*)(featb + (long)row * CDIM);
        const uint4* fj4 = (const uint4*)(featb + (long)col * CDIM);
        unsigned short* xr = sm.x1 + le * XS1;
        *(uint4*)(xr + sub * 16) = fi4[sub * 2];
        *(uint4*)(xr + sub * 16 + 8) = fi4[sub * 2 + 1];
        *(uint4*)(xr + 64 + sub * 16) = fj4[sub * 2];
        *(uint4*)(xr + 64 + sub * 16 + 8) = fj4[sub * 2 + 1];
        ushort4 z = {0, 0, 0, 0};
        if (sub == 0) {
            sm.rows[le] = row;
            sm.pos[le] = atomicAdd(&cursor[row], 1);  // cursor pre-seeded = rowstart
            float xix = coords[row * 3], xiy = coords[row * 3 + 1], xiz = coords[row * 3 + 2];
            float xjx = coords[col * 3], xjy = coords[col * 3 + 1], xjz = coords[col * 3 + 2];
            float rx = xix - xjx, ry = xiy - xjy, rz = xiz - xjz;
            float ux = u[0], uy = u[1], uz = u[2];
            float4 sc;
            sc.x = rx * rx + ry * ry + rz * rz;
            sc.y = xix * ux + xiy * uy + xiz * uz;
            sc.z = xjx * ux + xjy * uy + xjz * uz;
            sc.w = rx * ux + ry * uy + rz * uz;
            *(ushort4*)(xr + 128) = pack4(sc);
        } else if (sub == 1) {
            *(ushort4*)(xr + 132) = z; *(ushort4*)(xr + 136) = z; *(ushort4*)(xr + 140) = z;
        } else if (sub == 2) {
            *(ushort4*)(xr + 144) = z; *(ushort4*)(xr + 148) = z;
        } else {
            *(ushort4*)(xr + 152) = z; *(ushort4*)(xr + 156) = z;
        }
    }
    __syncthreads();

    floatx4 acc[8];

    // L1 (folded, K=160): reads slice @XS1, writes H1 into slice @HS
    bias_init<8>(acc, eb1, lane);
    mfma_layer<5, 8>(slice, XS1, frags + F1_OFF, lane, acc);
    epilogue_store<true, 8>(acc, slice, HS, lane);
    __syncthreads();

    // L2: H1 -> H2 (same slice; in-wave sequential)
    bias_init<8>(acc, eb2, lane);
    mfma_layer<4, 8>(slice, HS, frags + F2_OFF, lane, acc);
    epilogue_store<true, 8>(acc, slice, HS, lane);
    __syncthreads();

    // L3 -> h3 fp32 in regs + bf16 H3 back into slice for the gate GEMM
    floatx4 h3[8];
    bias_init<8>(h3, eb3, lane);
    mfma_layer<4, 8>(slice, HS, frags + F3_OFF, lane, h3);
    epilogue_store<false, 8>(h3, slice, HS, lane);
    __syncthreads();

    // Gate (reads bf16 H3 from slice)
    bias_init<8>(acc, gb1, lane);
    mfma_layer<4, 8>(slice, HS, frags + FG_OFF, lane, acc);
    {
        int q = lane >> 4, c = lane & 15;
        f32x2 p01 = {0.0f, 0.0f}, p23 = {0.0f, 0.0f};
#pragma unroll
        for (int ct = 0; ct < 8; ct++) {
            float w2 = gw2[ct * 16 + c];
            f32x2 g01 = gelu_pk((f32x2){acc[ct][0], acc[ct][1]});
            f32x2 g23 = gelu_pk((f32x2){acc[ct][2], acc[ct][3]});
            p01 += g01 * w2;
            p23 += g23 * w2;
        }
        float p[4] = {p01.x, p01.y, p23.x, p23.y};
#pragma unroll
        for (int i = 0; i < 4; i++) {
#pragma unroll
            for (int mask = 1; mask < 16; mask <<= 1) p[i] += __shfl_xor(p[i], mask, 64);
        }
        if (c == 0) {
            float gb = gb2[0];
#pragma unroll
            for (int i = 0; i < 4; i++) {
                float z = p[i] + gb;
                sm.gate[wv * 16 + q * 4 + i] = 1.0f / (1.0f + __expf(-z));
            }
        }
    }
    __syncthreads();

    if (use_msg) {
        {   // scaled bf16 message into slice (C->row layout) from h3 regs
            int q = lane >> 4, c = lane & 15;
            unsigned short* base = slice + (q * 4) * HS + c;
            float gv[4];
#pragma unroll
            for (int i = 0; i < 4; i++) gv[i] = sm.gate[wv * 16 + q * 4 + i];
#pragma unroll
            for (int ct = 0; ct < 8; ct++) {
                unsigned int p01 = f2bf2(h3[ct][0] * gv[0], h3[ct][1] * gv[1]);
                unsigned int p23 = f2bf2(h3[ct][2] * gv[2], h3[ct][3] * gv[3]);
                unsigned short* p = base + ct * 16;
                p[0] = (unsigned short)p01;
                p[HS] = (unsigned short)(p01 >> 16);
                p[2 * HS] = (unsigned short)p23;
                p[3 * HS] = (unsigned short)(p23 >> 16);
            }
        }
        __syncthreads();
        {   // coalesced 256B-row stream to msg[pos[e]]
            int le = t >> 2, sub = t & 3;
            long base = (long)sm.pos[le] * MCDIM;
            const unsigned short* src = sm.x1 + (le >> 4) * 16 * XS1 + (le & 15) * HS;
#pragma unroll
            for (int m = 0; m < 4; m++) {
                int off = m * 32 + sub * 8;
                *(short8*)(msg + base + off) = *(const short8*)(src + off);
            }
        }
    } else {
        int q = lane >> 4, c = lane & 15;
#pragma unroll
        for (int i = 0; i < 4; i++) {
            int e = wv * 16 + q * 4 + i;
            int row = sm.rows[e];
            float g = sm.gate[e];
            float* agr = agg + (long)row * MCDIM;
#pragma unroll
            for (int ct = 0; ct < 8; ct++)
                atomicAdd(agr + ct * 16 + c, g * h3[ct][i]);
        }
    }
}

// ---------------------------------------------------------------------------
// Gather: one wave per node; lane loads uint2 spanning TWO msg rows/iter.
// ---------------------------------------------------------------------------
__global__ __launch_bounds__(256) void gather_kernel(
    const int* __restrict__ rowstart, const unsigned short* __restrict__ msg,
    const float* __restrict__ agg, int use_msg,
    unsigned short* __restrict__ aggb) {
    int wv = threadIdx.x >> 6, lane = threadIdx.x & 63;
    int n = blockIdx.x * 4 + wv;
    if (n >= N_NODES) return;
    int rs = rowstart[n], re = rowstart[n + 1];
    int deg = re - rs;
    float a0 = 0.0f, a1 = 0.0f, a2 = 0.0f, a3 = 0.0f;
    if (use_msg) {
        const unsigned short* base = msg + (long)rs * MCDIM;
        int pairs = deg >> 1;
        for (int i = 0; i < pairs; i++) {
            uint2 v = *(const uint2*)(base + i * 256 + lane * 4);
            a0 += bf2f(v.x & 0xffffu); a1 += bf2f(v.x >> 16);
            a2 += bf2f(v.y & 0xffffu); a3 += bf2f(v.y >> 16);
        }
        if ((deg & 1) && lane < 32) {
            uint2 v = *(const uint2*)(base + (deg - 1) * MCDIM + lane * 4);
            a0 += bf2f(v.x & 0xffffu); a1 += bf2f(v.x >> 16);
            a2 += bf2f(v.y & 0xffffu); a3 += bf2f(v.y >> 16);
        }
        a0 += __shfl_xor(a0, 32, 64);
        a1 += __shfl_xor(a1, 32, 64);
        a2 += __shfl_xor(a2, 32, 64);
        a3 += __shfl_xor(a3, 32, 64);
    } else if (lane < 32) {
        const float4 v = *(const float4*)(agg + (long)n * MCDIM + lane * 4);
        a0 = v.x; a1 = v.y; a2 = v.z; a3 = v.w;
    }
    if (lane < 32) {
        float inv = 1.0f / fmaxf((float)deg, 1.0f);
        uint2 o;
        o.x = f2bf2(a0 * inv, a1 * inv);
        o.y = f2bf2(a2 * inv, a3 * inv);
        *(uint2*)(aggb + (long)n * MCDIM + lane * 4) = o;
    }
}

// ---------------------------------------------------------------------------
// MFMA node update: single-buffer slices. 64 nodes/block, 4 blocks/CU.
// ---------------------------------------------------------------------------
struct SmemU {
    unsigned short ui[64 * UST];   // 33792 B, all stages live here
};

__global__ __launch_bounds__(256, 4) void update_kernel(
    const unsigned short* __restrict__ featb, const unsigned short* __restrict__ aggb,
    const unsigned short* __restrict__ gctxb, const float* __restrict__ tres,
    const unsigned short* __restrict__ frags,
    const float* __restrict__ ub1, const float* __restrict__ ub2,
    const float* __restrict__ ub3,
    float* __restrict__ out) {
    __shared__ SmemU sm;
    int t = threadIdx.x;
    int wv = t >> 6;
    int lane = t & 63;
    int n0 = blockIdx.x * 64;
    unsigned short* slice = sm.ui + wv * 16 * UST;   // wave-private

    {   // stage [feat | agg | gctx] (all bf16 copies): 4 threads/node
        int ln = t >> 2, sub = t & 3;
        int n = n0 + ln;
        unsigned short* ur = sm.ui + ln * UST;
        if (n < N_NODES) {
            const uint4* f4 = (const uint4*)(featb + (long)n * CDIM);
            *(uint4*)(ur + sub * 16) = f4[sub * 2];
            *(uint4*)(ur + sub * 16 + 8) = f4[sub * 2 + 1];
            const uint4* a4 = (const uint4*)(aggb + (long)n * MCDIM);
            *(uint4*)(ur + 64 + sub * 32) = a4[sub * 4];
            *(uint4*)(ur + 64 + sub * 32 + 8) = a4[sub * 4 + 1];
            *(uint4*)(ur + 64 + sub * 32 + 16) = a4[sub * 4 + 2];
            *(uint4*)(ur + 64 + sub * 32 + 24) = a4[sub * 4 + 3];
            const uint4* g4 = (const uint4*)gctxb;
            *(uint4*)(ur + 192 + sub * 16) = g4[sub * 2];
            *(uint4*)(ur + 192 + sub * 16 + 8) = g4[sub * 2 + 1];
        } else {
            uint4 z = {0, 0, 0, 0};
#pragma unroll
            for (int m = 0; m < 8; m++) *(uint4*)(ur + sub * 64 + m * 8) = z;
        }
    }
    __syncthreads();

    floatx4 acc[8];
    bias_init<8>(acc, ub1, lane);
    mfma_layer<8, 8>(slice, UST, frags + FU1_OFF, lane, acc);
    epilogue_store<true, 8>(acc, slice, HS, lane);
    __syncthreads();

    bias_init<8>(acc, ub2, lane);
    mfma_layer<4, 8>(slice, HS, frags + FU2_OFF, lane, acc);
    epilogue_store<true, 8>(acc, slice, HS, lane);
    __syncthreads();

    floatx4 acc3[4];
    bias_init<4>(acc3, ub3, lane);
    mfma_layer<4, 4>(slice, HS, frags + FU3_OFF, lane, acc3);
    {
        int q = lane >> 4, c = lane & 15;
        float tr = *tres;
#pragma unroll
        for (int ct = 0; ct < 4; ct++) {
#pragma unroll
            for (int i = 0; i < 4; i++) {
                int n = n0 + wv * 16 + q * 4 + i;
                if (n < N_NODES) out[(long)n * CDIM + ct * 16 + c] = acc3[ct][i] * tr;
            }
        }
    }
}

// ---------------------------------------------------------------------------
extern "C" void kernel_launch(void* const* d_in, const int* in_sizes, int n_in,
                              void* d_out, int out_size, void* d_ws, size_t ws_size,
                              hipStream_t stream) {
    const float* coords = (const float*)d_in[0];
    const float* h = (const float*)d_in[1];
    const float* flow = (const float*)d_in[2];
    const int* eidx = (const int*)d_in[3];
    const float* ln_g = (const float*)d_in[4];
    const float* ln_b = (const float*)d_in[5];
    const float* ew1 = (const float*)d_in[6];
    const float* eb1 = (const float*)d_in[7];
    const float* ew2 = (const float*)d_in[8];
    const float* eb2 = (const float*)d_in[9];
    const float* ew3 = (const float*)d_in[10];
    const float* eb3 = (const float*)d_in[11];
    const float* gw1 = (const float*)d_in[12];
    const float* gb1 = (const float*)d_in[13];
    const float* gw2 = (const float*)d_in[14];
    const float* gb2 = (const float*)d_in[15];
    const float* glw1 = (const float*)d_in[16];
    const float* glb1 = (const float*)d_in[17];
    const float* glw2 = (const float*)d_in[18];
    const float* glb2 = (const float*)d_in[19];
    const float* glw3 = (const float*)d_in[20];
    const float* glb3 = (const float*)d_in[21];
    const float* uw1 = (const float*)d_in[22];
    const float* ub1 = (const float*)d_in[23];
    const float* uw2 = (const float*)d_in[24];
    const float* ub2 = (const float*)d_in[25];
    const float* uw3 = (const float*)d_in[26];
    const float* ub3 = (const float*)d_in[27];
    const float* res = (const float*)d_in[28];

    // ---- workspace carve-up ----
    char* base = (char*)d_ws;
    unsigned short* frags = (unsigned short*)base;                 // FRAG_TOTAL us
    unsigned short* featb = (unsigned short*)(base + FRAG_TOTAL * 2); // N*64 us
    unsigned short* aggb = featb + (size_t)N_NODES * CDIM;         // N*128 us
    unsigned short* gctxb = aggb + (size_t)N_NODES * MCDIM;        // 64 us
    float* gsum = (float*)(gctxb + 64);                            // 32*64
    float* u = gsum + GSUM_REP * 64;                               // 4
    float* tres = u + 4;                                           // 1
    int* rowstart = (int*)(tres + 1);                              // N+1
    int* cursor = rowstart + (N_NODES + 1);                        // N
    int* deg_int = cursor + N_NODES;                               // N
    char* tail = (char*)(deg_int + N_NODES);
    tail = (char*)(((uintptr_t)tail + 255) & ~(uintptr_t)255);
    size_t head_bytes = (size_t)(tail - base);
    size_t msg_bytes = (size_t)N_EDGES * MCDIM * 2;                // 204.8 MB bf16
    int use_msg = (ws_size >= head_bytes + msg_bytes) ? 1 : 0;
    unsigned short* msg = (unsigned short*)tail;                   // CSR slots
    float* agg = (float*)tail;                                     // fallback

    if (!use_msg)
        hipMemsetAsync(agg, 0, (size_t)N_NODES * MCDIM * sizeof(float), stream);

    prep_frags<<<FRAG_TOTAL / 256, 256, 0, stream>>>(ew1, ew2, ew3, gw1,
                                                     uw1, uw2, uw3, frags,
                                                     deg_int, gsum);
    ln_count_kernel<<<N_NODES / 4, 256, 0, stream>>>(h, ln_g, ln_b, flow, eidx,
                                                     featb, gsum, u, deg_int);
    mid_kernel<<<2, 1024, 0, stream>>>(deg_int, rowstart, cursor, gsum,
                                       glw1, glb1, glw2, glb2, glw3, glb3,
                                       res, gctxb, tres);
    edge_kernel<<<N_EDGES / 64, 256, 0, stream>>>(coords, eidx, featb, u, frags,
                                                  eb1, eb2, eb3, gb1, gw2, gb2,
                                                  cursor, msg, agg, use_msg);
    gather_kernel<<<(N_NODES + 3) / 4, 256, 0, stream>>>(rowstart, msg, agg,
                                                         use_msg, aggb);
    update_kernel<<<(N_NODES + 63) / 64, 256, 0, stream>>>(featb, aggb, gctxb,
                                                           tres, frags,
                                                           ub1, ub2, ub3,
                                                           (float*)d_out);
}

// Round 12
// 503.925 us; speedup vs baseline: 1.2849x; 1.0515x over previous
//
#include <hip/hip_runtime.h>
#include <hip/hip_bf16.h>
#include <math.h>

#define N_NODES 50000
#define N_EDGES 800000
#define CDIM 64
#define MCDIM 128
#define GSUM_REP 32   // gsum replication factor (atomic decontention)

// bf16 LDS strides (elements). Row stride in dwords must be == 4 (mod 8) so
// the 16-row A-fragment ds_read_b128 pattern lands 2 lanes/bank (free, m136).
#define XS1 168       // folded edge_input, K = 132 padded -> 160 (84 dw % 8 == 4)
#define HS  136       // hidden layers, K=128                (68 dw % 8 == 4)
#define UST 264       // update_input, K=256                (132 dw % 8 == 4)

typedef __attribute__((ext_vector_type(8))) short short8;
typedef __attribute__((ext_vector_type(4))) float floatx4;
typedef __attribute__((ext_vector_type(2))) float f32x2;

// A&S 7.1.27 erf (abs err 5e-4) gelu, scalar form (used in small kernels).
__device__ __forceinline__ float gelu_fast(float x) {
    float z = fabsf(x) * 0.70710678f;
    float w = fmaf(z, fmaf(z, fmaf(z, fmaf(z, 0.078108f, 0.000972f),
                                   0.230389f), 0.278393f), 1.0f);
    float w2 = w * w;
    float r = __builtin_amdgcn_rcpf(w2 * w2);
    float m = 0.5f * fabsf(x);
    return fmaf(-m, r, fmaf(0.5f, x, m));
}

// Packed-pair gelu: identical per-element math; float2 vector arithmetic lets
// LLVM emit dual-issue v_pk_{mul,add,fma}_f32. rcp stays scalar.
__device__ __forceinline__ f32x2 gelu_pk(f32x2 x) {
    f32x2 ax = __builtin_elementwise_abs(x);
    f32x2 z = ax * 0.70710678f;
    f32x2 w = z * (z * (z * (z * 0.078108f + 0.000972f) + 0.230389f)
                   + 0.278393f) + 1.0f;
    f32x2 w2 = w * w;
    f32x2 w4 = w2 * w2;
    f32x2 r;
    r.x = __builtin_amdgcn_rcpf(w4.x);
    r.y = __builtin_amdgcn_rcpf(w4.y);
    f32x2 m = 0.5f * ax;
    return 0.5f * x + m - m * r;
}

__device__ __forceinline__ unsigned short f2bf(float f) {  // RNE fp32->bf16
    unsigned int u = __float_as_uint(f);
    unsigned int r = u + 0x7fffu + ((u >> 16) & 1u);
    return (unsigned short)(r >> 16);
}
__device__ __forceinline__ float bf2f(unsigned int lo16) {
    return __uint_as_float(lo16 << 16);
}
// packed 2x fp32 -> bf16 pair (v_cvt_pk_bf16_f32 on gfx950)
__device__ __forceinline__ unsigned int f2bf2(float lo, float hi) {
    __hip_bfloat162 v = __float22bfloat162_rn(make_float2(lo, hi));
    union { __hip_bfloat162 b; unsigned int u; } cv;
    cv.b = v;
    return cv.u;
}
__device__ __forceinline__ ushort4 pack4(float4 v) {
    ushort4 r;
    r.x = f2bf(v.x); r.y = f2bf(v.y); r.z = f2bf(v.z); r.w = f2bf(v.w);
    return r;
}

// ---------------------------------------------------------------------------
// Weight fragment pre-swizzle. B-fragment for 16x16x32: lane l holds
// B[k = k0 + (l>>4)*8 + j][n = 16*ct + (l&15)], j=0..7 -> contiguous 16B/lane.
// ew1 is FOLDED: k<64 -> Wi+Wd ; 64..127 -> Wj-Wd ; 128..131 -> geo ; pad 160.
// FG chunk is COMPOSED: egw = ew3 @ gw1 (gate reads H2, H3 skips LDS).
// Also computes egb = eb3 @ gw1 + gb1 and zero-inits deg_int/gsum replicas.
// ---------------------------------------------------------------------------
#define F1_OFF 0               // folded ew1: 5 chunks (K=160), N=128
#define F2_OFF (5 * 4096)      // ew2: 4
#define F3_OFF (9 * 4096)      // ew3: 4
#define FG_OFF (13 * 4096)     // composed ew3@gw1: 4
#define FU1_OFF (17 * 4096)    // uw1: 8 (K=256)
#define FU2_OFF (25 * 4096)    // uw2: 4
#define FU3_OFF (29 * 4096)    // uw3: 4 chunks x 2048 (N=64)
#define FRAG_TOTAL (29 * 4096 + 4 * 2048)   // 126976 ushorts

__global__ __launch_bounds__(256) void prep_frags(
    const float* __restrict__ ew1, const float* __restrict__ ew2,
    const float* __restrict__ ew3, const float* __restrict__ gw1,
    const float* __restrict__ eb3, const float* __restrict__ gb1,
    const float* __restrict__ uw1, const float* __restrict__ uw2,
    const float* __restrict__ uw3, unsigned short* __restrict__ frags,
    int* __restrict__ deg_int, float* __restrict__ gsum,
    float* __restrict__ egb) {
    int idx = blockIdx.x * 256 + threadIdx.x;
    if (idx < N_NODES) deg_int[idx] = 0;
    if (idx < GSUM_REP * 64) gsum[idx] = 0.0f;
    if (idx < 128) {   // egb[n] = gb1[n] + eb3 . gw1[:,n]
        float s = gb1[idx];
        for (int jj = 0; jj < 128; jj++) s += eb3[jj] * gw1[jj * 128 + idx];
        egb[idx] = s;
    }
    if (idx >= FRAG_TOTAL) return;
    if (idx < F2_OFF) {  // folded ew1
        int chunk = idx >> 12;
        int rem = idx & 4095;
        int ct = rem >> 9;
        int lane = (rem >> 3) & 63;
        int j = rem & 7;
        int k = chunk * 32 + (lane >> 4) * 8 + j;
        int n = ct * 16 + (lane & 15);
        float v;
        if (k < 64)       v = ew1[k * 128 + n] + ew1[(128 + k) * 128 + n];
        else if (k < 128) v = ew1[k * 128 + n] - ew1[(64 + k) * 128 + n];
        else if (k < 132) v = ew1[(192 + k - 128) * 128 + n];
        else              v = 0.0f;
        frags[idx] = f2bf(v);
    } else if (idx >= FG_OFF && idx < FU1_OFF) {  // composed egw = ew3 @ gw1
        int chunk = idx >> 12;           // 13..16
        int rem = idx & 4095;
        int ct = rem >> 9;
        int lane = (rem >> 3) & 63;
        int j = rem & 7;
        int k = (chunk - 13) * 32 + (lane >> 4) * 8 + j;
        int n = ct * 16 + (lane & 15);
        float s = 0.0f;
        for (int jj = 0; jj < 128; jj++) s += ew3[k * 128 + jj] * gw1[jj * 128 + n];
        frags[idx] = f2bf(s);
    } else if (idx < FU3_OFF) {
        int chunk = idx >> 12;
        int rem = idx & 4095;
        int ct = rem >> 9;
        int lane = (rem >> 3) & 63;
        int j = rem & 7;
        const float* W; int kbase;
        if (chunk < 9)       { W = ew2; kbase = (chunk - 5) * 32; }
        else if (chunk < 13) { W = ew3; kbase = (chunk - 9) * 32; }
        else if (chunk < 25) { W = uw1; kbase = (chunk - 17) * 32; }
        else                 { W = uw2; kbase = (chunk - 25) * 32; }
        int k = kbase + (lane >> 4) * 8 + j;
        int n = ct * 16 + (lane & 15);
        frags[idx] = f2bf(W[k * 128 + n]);
    } else {  // uw3 [128][64]
        int rem = idx - FU3_OFF;
        int chunk = rem >> 11;
        int r = rem & 2047;
        int ct = r >> 9;
        int lane = (r >> 3) & 63;
        int j = r & 7;
        int k = chunk * 32 + (lane >> 4) * 8 + j;
        int n = ct * 16 + (lane & 15);
        frags[idx] = f2bf(uw3[k * 64 + n]);
    }
}

// ---------------------------------------------------------------------------
// MFMA helpers. acc init = column-broadcast bias.
// ---------------------------------------------------------------------------
template <int NCT>
__device__ __forceinline__ void bias_init(floatx4* acc,
                                          const float* __restrict__ bias, int lane) {
    int c = lane & 15;
#pragma unroll
    for (int ct = 0; ct < NCT; ct++) {
        float b = bias[ct * 16 + c];
        acc[ct][0] = b; acc[ct][1] = b; acc[ct][2] = b; acc[ct][3] = b;
    }
}

template <int NCH, int NCT>
__device__ __forceinline__ void mfma_layer(const unsigned short* Xl, int xs,
                                           const unsigned short* __restrict__ F,
                                           int lane, floatx4* acc) {
    int q = lane >> 4, c = lane & 15;
    const unsigned short* xrow = Xl + c * xs + q * 8;
    for (int k0 = 0; k0 < NCH; k0++) {
        short8 a = *(const short8*)(xrow + k0 * 32);
#pragma unroll
        for (int ct = 0; ct < NCT; ct++) {
            short8 b = *(const short8*)(F + ((k0 * NCT + ct) * 64 + lane) * 8);
            acc[ct] = __builtin_amdgcn_mfma_f32_16x16x32_bf16(a, b, acc[ct], 0, 0, 0);
        }
    }
}

// (opt) packed gelu + packed-bf16 store into an A-layout LDS tile.
// C layout: value (ct,i) at row (lane>>4)*4+i, col 16*ct+(lane&15).
template <bool GELU, int NCT>
__device__ __forceinline__ void epilogue_store(floatx4* acc,
                                               unsigned short* dst, int xs, int lane) {
    int q = lane >> 4, c = lane & 15;
    unsigned short* base = dst + (q * 4) * xs + c;
#pragma unroll
    for (int ct = 0; ct < NCT; ct++) {
        f32x2 v01 = {acc[ct][0], acc[ct][1]};
        f32x2 v23 = {acc[ct][2], acc[ct][3]};
        if (GELU) { v01 = gelu_pk(v01); v23 = gelu_pk(v23); }
        unsigned int p01 = f2bf2(v01.x, v01.y), p23 = f2bf2(v23.x, v23.y);
        unsigned short* p = base + ct * 16;
        p[0]      = (unsigned short)p01;
        p[xs]     = (unsigned short)(p01 >> 16);
        p[2 * xs] = (unsigned short)p23;
        p[3 * xs] = (unsigned short)(p23 >> 16);
    }
}

// ---------------------------------------------------------------------------
// LayerNorm (bf16 out) + global-mean partials (replicated atomics)
// + flow_dir normalize + degree
// ---------------------------------------------------------------------------
__global__ __launch_bounds__(256) void ln_count_kernel(
    const float* __restrict__ h, const float* __restrict__ ln_g,
    const float* __restrict__ ln_b, const float* __restrict__ flow_dir,
    const int* __restrict__ eidx, unsigned short* __restrict__ featb,
    float* __restrict__ gsum, float* __restrict__ u_out,
    int* __restrict__ deg_int) {
    int t = threadIdx.x;
    int ln = t >> 6;
    int c = t & 63;
    int n = blockIdx.x * 4 + ln;

    float x = h[n * CDIM + c];
    float s = x;
#pragma unroll
    for (int off = 32; off > 0; off >>= 1) s += __shfl_xor(s, off, 64);
    float mu = s * (1.0f / 64.0f);
    float d = x - mu;
    float v = d * d;
#pragma unroll
    for (int off = 32; off > 0; off >>= 1) v += __shfl_xor(v, off, 64);
    float rs = 1.0f / sqrtf(v * (1.0f / 64.0f) + 1e-5f);
    float f = d * rs * ln_g[c] + ln_b[c];
    featb[n * CDIM + c] = f2bf(f);

    __shared__ float fs[4][64];
    fs[ln][c] = f;
    __syncthreads();   // cross-wave reduction below
    if (t < 64) {
        float p = fs[0][t] + fs[1][t] + fs[2][t] + fs[3][t];
        atomicAdd(&gsum[(blockIdx.x & (GSUM_REP - 1)) * 64 + t], p);
        int e = blockIdx.x * 64 + t;           // 12500*64 == N_EDGES
        atomicAdd(&deg_int[eidx[e]], 1);
    }
    if (blockIdx.x == 0 && t == 0) {
        float ux = flow_dir[0], uy = flow_dir[1], uz = flow_dir[2];
        float nrm = sqrtf(ux * ux + uy * uy + uz * uz) + 1e-8f;
        u_out[0] = ux / nrm;
        u_out[1] = uy / nrm;
        u_out[2] = uz / nrm;
    }
}

// ---------------------------------------------------------------------------
// Merged mid kernel: block 0 = exclusive prefix scan; block 1 = global MLP
// (first reducing the gsum replicas).
// ---------------------------------------------------------------------------
__global__ __launch_bounds__(1024) void mid_kernel(
    const int* __restrict__ deg_int, int* __restrict__ rowstart,
    int* __restrict__ cursor,
    const float* __restrict__ gsum,
    const float* __restrict__ glw1, const float* __restrict__ glb1,
    const float* __restrict__ glw2, const float* __restrict__ glb2,
    const float* __restrict__ glw3, const float* __restrict__ glb3,
    const float* __restrict__ res_scale,
    unsigned short* __restrict__ gctxb, float* __restrict__ tres) {
    int t = threadIdx.x;
    if (blockIdx.x == 0) {
        __shared__ int wsum[16];
        __shared__ int run;
        int wid = t >> 6, lane = t & 63;
        int4 vs[13];
#pragma unroll
        for (int chunk = 0; chunk < 13; chunk++) {
            int base = chunk * 4096 + t * 4;
            int4 v = {0, 0, 0, 0};
            if (base + 3 < N_NODES) {
                v = *(const int4*)(deg_int + base);
            } else {
                if (base < N_NODES) v.x = deg_int[base];
                if (base + 1 < N_NODES) v.y = deg_int[base + 1];
                if (base + 2 < N_NODES) v.z = deg_int[base + 2];
                if (base + 3 < N_NODES) v.w = deg_int[base + 3];
            }
            vs[chunk] = v;
        }
        if (t == 0) run = 0;
        __syncthreads();
#pragma unroll
        for (int chunk = 0; chunk < 13; chunk++) {
            int base = chunk * 4096 + t * 4;
            int4 v = vs[chunk];
            int s1 = v.x, s2 = s1 + v.y, s3 = s2 + v.z, s4 = s3 + v.w;
            int x = s4;
#pragma unroll
            for (int off = 1; off < 64; off <<= 1) {
                int y = __shfl_up(x, off, 64);
                if (lane >= off) x += y;
            }
            if (lane == 63) wsum[wid] = x;
            __syncthreads();
            if (t < 16) {
                int sv = wsum[t];
#pragma unroll
                for (int off = 1; off < 16; off <<= 1) {
                    int y = __shfl_up(sv, off, 16);
                    if (t >= off) sv += y;
                }
                wsum[t] = sv;
            }
            __syncthreads();
            int run_l = run;
            int wpre = (wid == 0) ? 0 : wsum[wid - 1];
            int toff = run_l + wpre + (x - s4);
            int e0 = toff, e1 = toff + s1, e2 = toff + s2, e3 = toff + s3;
            if (base <= N_NODES) rowstart[base] = e0;
            if (base + 1 <= N_NODES) rowstart[base + 1] = e1;
            if (base + 2 <= N_NODES) rowstart[base + 2] = e2;
            if (base + 3 <= N_NODES) rowstart[base + 3] = e3;
            if (base < N_NODES) cursor[base] = e0;
            if (base + 1 < N_NODES) cursor[base + 1] = e1;
            if (base + 2 < N_NODES) cursor[base + 2] = e2;
            if (base + 3 < N_NODES) cursor[base + 3] = e3;
            __syncthreads();
            if (t == 0) run = run_l + wsum[15];
            __syncthreads();
        }
    } else {
        __shared__ float a[64], b[64];
        float s = 0.0f;
        if (t < 64) {
            float acc = 0.0f;
            for (int r = 0; r < GSUM_REP; r++) acc += gsum[r * 64 + t];
            a[t] = acc * (1.0f / (float)N_NODES);
        }
        __syncthreads();
        if (t < 64) {
            s = glb1[t];
            for (int k = 0; k < 64; k++) s += a[k] * glw1[k * 64 + t];
            b[t] = gelu_fast(s);
        }
        __syncthreads();
        if (t < 64) {
            s = glb2[t];
            for (int k = 0; k < 64; k++) s += b[k] * glw2[k * 64 + t];
        }
        __syncthreads();
        if (t < 64) a[t] = gelu_fast(s);
        __syncthreads();
        if (t < 64) {
            s = glb3[t];
            for (int k = 0; k < 64; k++) s += a[k] * glw3[k * 64 + t];
            gctxb[t] = f2bf(s);
        }
        if (t == 0) *tres = tanhf(res_scale[0]);
    }
}

// ---------------------------------------------------------------------------
// Fused MFMA edge pipeline: 64 edges/block, 4 waves x 16 rows.
// Composed gate weights (egw = ew3@gw1): the gate GEMM reads H2, so H3 never
// round-trips through LDS — it lives in fp32 regs and is scaled-stored once.
// Phase chain: stage | L1 | L2 | {gate, L3} | scaled-store | stream.
// Barriers 6 -> 4. Single wave-private LDS slice, launch_bounds(256,5).
// ---------------------------------------------------------------------------
struct SmemE {
    unsigned short x1[64 * XS1];   // 21504 B, all pipeline stages live here
    float gate[64];
    int pos[64];
    int rows[64];
};

__global__ __launch_bounds__(256, 5) void edge_kernel(
    const float* __restrict__ coords, const int* __restrict__ eidx,
    const unsigned short* __restrict__ featb, const float* __restrict__ u,
    const unsigned short* __restrict__ frags,
    const float* __restrict__ eb1, const float* __restrict__ eb2,
    const float* __restrict__ eb3,
    const float* __restrict__ egb, const float* __restrict__ gw2,
    const float* __restrict__ gb2,
    int* __restrict__ cursor, unsigned short* __restrict__ msg,
    float* __restrict__ agg, int use_msg) {
    __shared__ SmemE sm;
    int t = threadIdx.x;
    int wv = t >> 6;
    int lane = t & 63;
    int e0 = blockIdx.x * 64;
    unsigned short* slice = sm.x1 + wv * 16 * XS1;   // wave-private

    {   // stage folded edge_input (bf16 copies, no cvt): 4 threads/edge
        int le = t >> 2, sub = t & 3;
        int e = e0 + le;
        int row = eidx[e];
        int col = eidx[N_EDGES + e];
        const uint4* fi4 = (const uint4*)(featb + (long)row * CDIM);
        const uint4* fj4 = (const uint4*)(featb + (long)col * CDIM);
        unsigned short* xr = sm.x1 + le * XS1;
        *(uint4*)(xr + sub * 16) = fi4[sub * 2];
        *(uint4*)(xr + sub * 16 + 8) = fi4[sub * 2 + 1];
        *(uint4*)(xr + 64 + sub * 16) = fj4[sub * 2];
        *(uint4*)(xr + 64 + sub * 16 + 8) = fj4[sub * 2 + 1];
        ushort4 z = {0, 0, 0, 0};
        if (sub == 0) {
            sm.rows[le] = row;
            sm.pos[le] = atomicAdd(&cursor[row], 1);  // cursor pre-seeded = rowstart
            float xix = coords[row * 3], xiy = coords[row * 3 + 1], xiz = coords[row * 3 + 2];
            float xjx = coords[col * 3], xjy = coords[col * 3 + 1], xjz = coords[col * 3 + 2];
            float rx = xix - xjx, ry = xiy - xjy, rz = xiz - xjz;
            float ux = u[0], uy = u[1], uz = u[2];
            float4 sc;
            sc.x = rx * rx + ry * ry + rz * rz;
            sc.y = xix * ux + xiy * uy + xiz * uz;
            sc.z = xjx * ux + xjy * uy + xjz * uz;
            sc.w = rx * ux + ry * uy + rz * uz;
            *(ushort4*)(xr + 128) = pack4(sc);
        } else if (sub == 1) {
            *(ushort4*)(xr + 132) = z; *(ushort4*)(xr + 136) = z; *(ushort4*)(xr + 140) = z;
        } else if (sub == 2) {
            *(ushort4*)(xr + 144) = z; *(ushort4*)(xr + 148) = z;
        } else {
            *(ushort4*)(xr + 152) = z; *(ushort4*)(xr + 156) = z;
        }
    }
    __syncthreads();

    floatx4 acc[8];

    // L1 (folded, K=160): reads slice @XS1, writes H1 into slice @HS
    bias_init<8>(acc, eb1, lane);
    mfma_layer<5, 8>(slice, XS1, frags + F1_OFF, lane, acc);
    epilogue_store<true, 8>(acc, slice, HS, lane);
    __syncthreads();

    // L2: H1 -> H2 (same slice; in-wave sequential)
    bias_init<8>(acc, eb2, lane);
    mfma_layer<4, 8>(slice, HS, frags + F2_OFF, lane, acc);
    epilogue_store<true, 8>(acc, slice, HS, lane);
    __syncthreads();

    // Gate: G1 = H2 @ (ew3.gw1) + egb  (composed; reads H2, not H3)
    bias_init<8>(acc, egb, lane);
    mfma_layer<4, 8>(slice, HS, frags + FG_OFF, lane, acc);
    {
        int q = lane >> 4, c = lane & 15;
        f32x2 p01 = {0.0f, 0.0f}, p23 = {0.0f, 0.0f};
#pragma unroll
        for (int ct = 0; ct < 8; ct++) {
            float w2 = gw2[ct * 16 + c];
            f32x2 g01 = gelu_pk((f32x2){acc[ct][0], acc[ct][1]});
            f32x2 g23 = gelu_pk((f32x2){acc[ct][2], acc[ct][3]});
            p01 += g01 * w2;
            p23 += g23 * w2;
        }
        float p[4] = {p01.x, p01.y, p23.x, p23.y};
#pragma unroll
        for (int i = 0; i < 4; i++) {
#pragma unroll
            for (int mask = 1; mask < 16; mask <<= 1) p[i] += __shfl_xor(p[i], mask, 64);
        }
        if (c == 0) {
            float gb = gb2[0];
#pragma unroll
            for (int i = 0; i < 4; i++) {
                float z = p[i] + gb;
                sm.gate[wv * 16 + q * 4 + i] = 1.0f / (1.0f + __expf(-z));
            }
        }
    }

    // L3: H2 -> h3 (fp32 regs only; H3 never written to LDS unscaled)
    floatx4 h3[8];
    bias_init<8>(h3, eb3, lane);
    mfma_layer<4, 8>(slice, HS, frags + F3_OFF, lane, h3);

    if (use_msg) {
        {   // scaled bf16 message into slice (C->row layout) from h3 regs
            int q = lane >> 4, c = lane & 15;
            unsigned short* base = slice + (q * 4) * HS + c;
            float gv[4];
#pragma unroll
            for (int i = 0; i < 4; i++) gv[i] = sm.gate[wv * 16 + q * 4 + i];
#pragma unroll
            for (int ct = 0; ct < 8; ct++) {
                unsigned int p01 = f2bf2(h3[ct][0] * gv[0], h3[ct][1] * gv[1]);
                unsigned int p23 = f2bf2(h3[ct][2] * gv[2], h3[ct][3] * gv[3]);
                unsigned short* p = base + ct * 16;
                p[0] = (unsigned short)p01;
                p[HS] = (unsigned short)(p01 >> 16);
                p[2 * HS] = (unsigned short)p23;
                p[3 * HS] = (unsigned short)(p23 >> 16);
            }
        }
        __syncthreads();
        {   // coalesced 256B-row stream to msg[pos[e]]
            int le = t >> 2, sub = t & 3;
            long base = (long)sm.pos[le] * MCDIM;
            const unsigned short* src = sm.x1 + (le >> 4) * 16 * XS1 + (le & 15) * HS;
#pragma unroll
            for (int m = 0; m < 4; m++) {
                int off = m * 32 + sub * 8;
                *(short8*)(msg + base + off) = *(const short8*)(src + off);
            }
        }
    } else {
        int q = lane >> 4, c = lane & 15;
#pragma unroll
        for (int i = 0; i < 4; i++) {
            int e = wv * 16 + q * 4 + i;
            int row = sm.rows[e];
            float g = sm.gate[e];
            float* agr = agg + (long)row * MCDIM;
#pragma unroll
            for (int ct = 0; ct < 8; ct++)
                atomicAdd(agr + ct * 16 + c, g * h3[ct][i]);
        }
    }
}

// ---------------------------------------------------------------------------
// Gather: one wave per node; lane loads uint2 spanning TWO msg rows/iter.
// ---------------------------------------------------------------------------
__global__ __launch_bounds__(256) void gather_kernel(
    const int* __restrict__ rowstart, const unsigned short* __restrict__ msg,
    const float* __restrict__ agg, int use_msg,
    unsigned short* __restrict__ aggb) {
    int wv = threadIdx.x >> 6, lane = threadIdx.x & 63;
    int n = blockIdx.x * 4 + wv;
    if (n >= N_NODES) return;
    int rs = rowstart[n], re = rowstart[n + 1];
    int deg = re - rs;
    float a0 = 0.0f, a1 = 0.0f, a2 = 0.0f, a3 = 0.0f;
    if (use_msg) {
        const unsigned short* base = msg + (long)rs * MCDIM;
        int pairs = deg >> 1;
        for (int i = 0; i < pairs; i++) {
            uint2 v = *(const uint2*)(base + i * 256 + lane * 4);
            a0 += bf2f(v.x & 0xffffu); a1 += bf2f(v.x >> 16);
            a2 += bf2f(v.y & 0xffffu); a3 += bf2f(v.y >> 16);
        }
        if ((deg & 1) && lane < 32) {
            uint2 v = *(const uint2*)(base + (deg - 1) * MCDIM + lane * 4);
            a0 += bf2f(v.x & 0xffffu); a1 += bf2f(v.x >> 16);
            a2 += bf2f(v.y & 0xffffu); a3 += bf2f(v.y >> 16);
        }
        a0 += __shfl_xor(a0, 32, 64);
        a1 += __shfl_xor(a1, 32, 64);
        a2 += __shfl_xor(a2, 32, 64);
        a3 += __shfl_xor(a3, 32, 64);
    } else if (lane < 32) {
        const float4 v = *(const float4*)(agg + (long)n * MCDIM + lane * 4);
        a0 = v.x; a1 = v.y; a2 = v.z; a3 = v.w;
    }
    if (lane < 32) {
        float inv = 1.0f / fmaxf((float)deg, 1.0f);
        uint2 o;
        o.x = f2bf2(a0 * inv, a1 * inv);
        o.y = f2bf2(a2 * inv, a3 * inv);
        *(uint2*)(aggb + (long)n * MCDIM + lane * 4) = o;
    }
}

// ---------------------------------------------------------------------------
// MFMA node update: single-buffer slices. 64 nodes/block, 4 blocks/CU.
// ---------------------------------------------------------------------------
struct SmemU {
    unsigned short ui[64 * UST];   // 33792 B, all stages live here
};

__global__ __launch_bounds__(256, 4) void update_kernel(
    const unsigned short* __restrict__ featb, const unsigned short* __restrict__ aggb,
    const unsigned short* __restrict__ gctxb, const float* __restrict__ tres,
    const unsigned short* __restrict__ frags,
    const float* __restrict__ ub1, const float* __restrict__ ub2,
    const float* __restrict__ ub3,
    float* __restrict__ out) {
    __shared__ SmemU sm;
    int t = threadIdx.x;
    int wv = t >> 6;
    int lane = t & 63;
    int n0 = blockIdx.x * 64;
    unsigned short* slice = sm.ui + wv * 16 * UST;   // wave-private

    {   // stage [feat | agg | gctx] (all bf16 copies): 4 threads/node
        int ln = t >> 2, sub = t & 3;
        int n = n0 + ln;
        unsigned short* ur = sm.ui + ln * UST;
        if (n < N_NODES) {
            const uint4* f4 = (const uint4*)(featb + (long)n * CDIM);
            *(uint4*)(ur + sub * 16) = f4[sub * 2];
            *(uint4*)(ur + sub * 16 + 8) = f4[sub * 2 + 1];
            const uint4* a4 = (const uint4*)(aggb + (long)n * MCDIM);
            *(uint4*)(ur + 64 + sub * 32) = a4[sub * 4];
            *(uint4*)(ur + 64 + sub * 32 + 8) = a4[sub * 4 + 1];
            *(uint4*)(ur + 64 + sub * 32 + 16) = a4[sub * 4 + 2];
            *(uint4*)(ur + 64 + sub * 32 + 24) = a4[sub * 4 + 3];
            const uint4* g4 = (const uint4*)gctxb;
            *(uint4*)(ur + 192 + sub * 16) = g4[sub * 2];
            *(uint4*)(ur + 192 + sub * 16 + 8) = g4[sub * 2 + 1];
        } else {
            uint4 z = {0, 0, 0, 0};
#pragma unroll
            for (int m = 0; m < 8; m++) *(uint4*)(ur + sub * 64 + m * 8) = z;
        }
    }
    __syncthreads();

    floatx4 acc[8];
    bias_init<8>(acc, ub1, lane);
    mfma_layer<8, 8>(slice, UST, frags + FU1_OFF, lane, acc);
    epilogue_store<true, 8>(acc, slice, HS, lane);
    __syncthreads();

    bias_init<8>(acc, ub2, lane);
    mfma_layer<4, 8>(slice, HS, frags + FU2_OFF, lane, acc);
    epilogue_store<true, 8>(acc, slice, HS, lane);
    __syncthreads();

    floatx4 acc3[4];
    bias_init<4>(acc3, ub3, lane);
    mfma_layer<4, 4>(slice, HS, frags + FU3_OFF, lane, acc3);
    {
        int q = lane >> 4, c = lane & 15;
        float tr = *tres;
#pragma unroll
        for (int ct = 0; ct < 4; ct++) {
#pragma unroll
            for (int i = 0; i < 4; i++) {
                int n = n0 + wv * 16 + q * 4 + i;
                if (n < N_NODES) out[(long)n * CDIM + ct * 16 + c] = acc3[ct][i] * tr;
            }
        }
    }
}

// ---------------------------------------------------------------------------
extern "C" void kernel_launch(void* const* d_in, const int* in_sizes, int n_in,
                              void* d_out, int out_size, void* d_ws, size_t ws_size,
                              hipStream_t stream) {
    const float* coords = (const float*)d_in[0];
    const float* h = (const float*)d_in[1];
    const float* flow = (const float*)d_in[2];
    const int* eidx = (const int*)d_in[3];
    const float* ln_g = (const float*)d_in[4];
    const float* ln_b = (const float*)d_in[5];
    const float* ew1 = (const float*)d_in[6];
    const float* eb1 = (const float*)d_in[7];
    const float* ew2 = (const float*)d_in[8];
    const float* eb2 = (const float*)d_in[9];
    const float* ew3 = (const float*)d_in[10];
    const float* eb3 = (const float*)d_in[11];
    const float* gw1 = (const float*)d_in[12];
    const float* gb1 = (const float*)d_in[13];
    const float* gw2 = (const float*)d_in[14];
    const float* gb2 = (const float*)d_in[15];
    const float* glw1 = (const float*)d_in[16];
    const float* glb1 = (const float*)d_in[17];
    const float* glw2 = (const float*)d_in[18];
    const float* glb2 = (const float*)d_in[19];
    const float* glw3 = (const float*)d_in[20];
    const float* glb3 = (const float*)d_in[21];
    const float* uw1 = (const float*)d_in[22];
    const float* ub1 = (const float*)d_in[23];
    const float* uw2 = (const float*)d_in[24];
    const float* ub2 = (const float*)d_in[25];
    const float* uw3 = (const float*)d_in[26];
    const float* ub3 = (const float*)d_in[27];
    const float* res = (const float*)d_in[28];

    // ---- workspace carve-up ----
    char* base = (char*)d_ws;
    unsigned short* frags = (unsigned short*)base;                 // FRAG_TOTAL us
    unsigned short* featb = (unsigned short*)(base + FRAG_TOTAL * 2); // N*64 us
    unsigned short* aggb = featb + (size_t)N_NODES * CDIM;         // N*128 us
    unsigned short* gctxb = aggb + (size_t)N_NODES * MCDIM;        // 64 us
    float* gsum = (float*)(gctxb + 64);                            // 32*64
    float* u = gsum + GSUM_REP * 64;                               // 4
    float* tres = u + 4;                                           // 1
    float* egb = tres + 1;                                         // 128
    int* rowstart = (int*)(egb + 128);                             // N+1
    int* cursor = rowstart + (N_NODES + 1);                        // N
    int* deg_int = cursor + N_NODES;                               // N
    char* tail = (char*)(deg_int + N_NODES);
    tail = (char*)(((uintptr_t)tail + 255) & ~(uintptr_t)255);
    size_t head_bytes = (size_t)(tail - base);
    size_t msg_bytes = (size_t)N_EDGES * MCDIM * 2;                // 204.8 MB bf16
    int use_msg = (ws_size >= head_bytes + msg_bytes) ? 1 : 0;
    unsigned short* msg = (unsigned short*)tail;                   // CSR slots
    float* agg = (float*)tail;                                     // fallback

    if (!use_msg)
        hipMemsetAsync(agg, 0, (size_t)N_NODES * MCDIM * sizeof(float), stream);

    prep_frags<<<FRAG_TOTAL / 256, 256, 0, stream>>>(ew1, ew2, ew3, gw1,
                                                     eb3, gb1,
                                                     uw1, uw2, uw3, frags,
                                                     deg_int, gsum, egb);
    ln_count_kernel<<<N_NODES / 4, 256, 0, stream>>>(h, ln_g, ln_b, flow, eidx,
                                                     featb, gsum, u, deg_int);
    mid_kernel<<<2, 1024, 0, stream>>>(deg_int, rowstart, cursor, gsum,
                                       glw1, glb1, glw2, glb2, glw3, glb3,
                                       res, gctxb, tres);
    edge_kernel<<<N_EDGES / 64, 256, 0, stream>>>(coords, eidx, featb, u, frags,
                                                  eb1, eb2, eb3, egb, gw2, gb2,
                                                  cursor, msg, agg, use_msg);
    gather_kernel<<<(N_NODES + 3) / 4, 256, 0, stream>>>(rowstart, msg, agg,
                                                         use_msg, aggb);
    update_kernel<<<(N_NODES + 63) / 64, 256, 0, stream>>>(featb, aggb, gctxb,
                                                           tres, frags,
                                                           ub1, ub2, ub3,
                                                           (float*)d_out);
}